// Round 1
// baseline (4077.892 us; speedup 1.0000x reference)
//
#include <hip/hip_runtime.h>
#include <hip/hip_bf16.h>

#define N_NODES 100000
#define IN_C 256
#define HID 128
#define OUT_C 40

constexpr int TILE = 64;
constexpr int KCH  = 64;
constexpr int LP   = KCH + 4;   // padded row len for [TILE][LP] layouts (16B-aligned rows)
constexpr int TP   = TILE + 4;  // padded for [KCH][TP] layouts

// ---------------- count / prep ----------------
__global__ __launch_bounds__(256) void count_k(const int* __restrict__ ei, int E, float* __restrict__ cnt) {
    int i = blockIdx.x * 256 + threadIdx.x;
    if (i >= E) return;
    int dst = ei[E + i];
    if ((unsigned)dst < (unsigned)N_NODES)
        unsafeAtomicAdd(&cnt[dst], 1.0f);
}

__global__ __launch_bounds__(256) void prep_k(float* __restrict__ cnt, float* __restrict__ inv, int n) {
    int i = blockIdx.x * 256 + threadIdx.x;
    if (i >= n) return;
    float c = fmaxf(cnt[i], 1.0f);
    cnt[i] = c;          // cnt now holds cmax
    inv[i] = 1.0f / c;
}

// ---------------- fused GEMM: Y = X@Wl^T ; Z = (X@Wr^T + b) * cmax ----------------
// X [nrows,K] row-major; Wl/Wr [half,K]; Y,Z [nrows,half]
__global__ __launch_bounds__(256) void gemm_split(
    const float* __restrict__ X, int K,
    const float* __restrict__ Wl, const float* __restrict__ Wr,
    const float* __restrict__ bias,
    const float* __restrict__ cmax,
    float* __restrict__ Y, float* __restrict__ Z,
    int half, int nrows)
{
    __shared__ float Xs[KCH][TP];   // k-major: Xs[k][row]
    __shared__ float Ws[KCH][TP];   // k-major: Ws[k][col]
    const int rowTile = blockIdx.x * TILE;
    const int colTile = blockIdx.y * TILE;
    const int tx = threadIdx.x;
    const int tc = tx & 15, tr = tx >> 4;
    const int ncols = 2 * half;
    float acc[4][4] = {};

    for (int k0 = 0; k0 < K; k0 += KCH) {
        #pragma unroll
        for (int i = 0; i < 4; ++i) {
            int idx = i * 256 + tx;
            int row = idx >> 4, kq = idx & 15;   // row 0..63, kq 0..15 (float4 along K)
            // X tile (transpose on store)
            float4 v = make_float4(0.f, 0.f, 0.f, 0.f);
            int gr = rowTile + row;
            if (gr < nrows) v = *(const float4*)&X[(size_t)gr * K + k0 + kq * 4];
            Xs[kq*4+0][row] = v.x; Xs[kq*4+1][row] = v.y;
            Xs[kq*4+2][row] = v.z; Xs[kq*4+3][row] = v.w;
            // W tile (transpose on store)
            float4 w = make_float4(0.f, 0.f, 0.f, 0.f);
            int wc = colTile + row;
            if (wc < ncols) {
                const float* Wp = (wc < half) ? &Wl[(size_t)wc * K] : &Wr[(size_t)(wc - half) * K];
                w = *(const float4*)&Wp[k0 + kq * 4];
            }
            Ws[kq*4+0][row] = w.x; Ws[kq*4+1][row] = w.y;
            Ws[kq*4+2][row] = w.z; Ws[kq*4+3][row] = w.w;
        }
        __syncthreads();
        #pragma unroll 8
        for (int k = 0; k < KCH; ++k) {
            float4 a = *(const float4*)&Xs[k][tr * 4];
            float4 b = *(const float4*)&Ws[k][tc * 4];
            acc[0][0] += a.x*b.x; acc[0][1] += a.x*b.y; acc[0][2] += a.x*b.z; acc[0][3] += a.x*b.w;
            acc[1][0] += a.y*b.x; acc[1][1] += a.y*b.y; acc[1][2] += a.y*b.z; acc[1][3] += a.y*b.w;
            acc[2][0] += a.z*b.x; acc[2][1] += a.z*b.y; acc[2][2] += a.z*b.z; acc[2][3] += a.z*b.w;
            acc[3][0] += a.w*b.x; acc[3][1] += a.w*b.y; acc[3][2] += a.w*b.z; acc[3][3] += a.w*b.w;
        }
        __syncthreads();
    }

    #pragma unroll
    for (int i = 0; i < 4; ++i) {
        int row = rowTile + tr * 4 + i;
        if (row >= nrows) continue;
        float cm = cmax[row];
        #pragma unroll
        for (int j = 0; j < 4; ++j) {
            int col = colTile + tc * 4 + j;
            if (col < half) {
                Y[(size_t)row * half + col] = acc[i][j];
            } else if (col < ncols) {
                int c = col - half;
                Z[(size_t)row * half + c] = (acc[i][j] + bias[c]) * cm;
            }
        }
    }
}

// ---------------- scatter: AG[dst] += Y[src], 128 feats ----------------
__global__ __launch_bounds__(256) void scatter128(const int* __restrict__ ei, int E,
                                                  const float* __restrict__ Y, float* __restrict__ AG) {
    long long gid = (long long)blockIdx.x * 256 + threadIdx.x;
    int e = (int)(gid >> 5);
    int t = (int)(gid & 31);
    if (e >= E) return;
    int src = ei[e], dst = ei[E + e];
    if ((unsigned)src >= (unsigned)N_NODES || (unsigned)dst >= (unsigned)N_NODES) return;
    float4 v = *(const float4*)&Y[(size_t)src * 128 + t * 4];
    float* p = &AG[(size_t)dst * 128 + t * 4];
    unsafeAtomicAdd(p + 0, v.x);
    unsafeAtomicAdd(p + 1, v.y);
    unsafeAtomicAdd(p + 2, v.z);
    unsafeAtomicAdd(p + 3, v.w);
}

// ---------------- scatter: AG[dst] += Y[src], 40 feats ----------------
__global__ __launch_bounds__(256) void scatter40(const int* __restrict__ ei, int E,
                                                 const float* __restrict__ Y, float* __restrict__ AG) {
    long long gid = (long long)blockIdx.x * 256 + threadIdx.x;
    int e = (int)(gid >> 4);
    int t = (int)(gid & 15);
    if (e >= E || t >= 10) return;
    int src = ei[e], dst = ei[E + e];
    if ((unsigned)src >= (unsigned)N_NODES || (unsigned)dst >= (unsigned)N_NODES) return;
    float4 v = *(const float4*)&Y[(size_t)src * 40 + t * 4];
    float* p = &AG[(size_t)dst * 40 + t * 4];
    unsafeAtomicAdd(p + 0, v.x);
    unsafeAtomicAdd(p + 1, v.y);
    unsafeAtomicAdd(p + 2, v.z);
    unsafeAtomicAdd(p + 3, v.w);
}

// ---------------- finalize layer1: H = relu(AG * inv), in place ----------------
__global__ __launch_bounds__(256) void relu_fin(float* __restrict__ AG, const float* __restrict__ inv, int n4) {
    int i = blockIdx.x * 256 + threadIdx.x;
    if (i >= n4) return;
    int node = i >> 5;               // 32 float4 per 128-float row
    float s = inv[node];
    float4 v = *(float4*)&AG[i * 4];
    v.x = fmaxf(v.x * s, 0.f); v.y = fmaxf(v.y * s, 0.f);
    v.z = fmaxf(v.z * s, 0.f); v.w = fmaxf(v.w * s, 0.f);
    *(float4*)&AG[i * 4] = v;
}

// ---------------- log_softmax over 40 classes, one wave per node ----------------
__global__ __launch_bounds__(256) void logsm_k(const float* __restrict__ AG, const float* __restrict__ inv,
                                               float* __restrict__ out, int n) {
    int node = blockIdx.x * 4 + (threadIdx.x >> 6);
    int lane = threadIdx.x & 63;
    if (node >= n) return;
    float iv = inv[node];
    float o = -INFINITY;
    if (lane < OUT_C) o = AG[(size_t)node * OUT_C + lane] * iv;
    float m = o;
    #pragma unroll
    for (int off = 32; off; off >>= 1) m = fmaxf(m, __shfl_xor(m, off));
    float e = (lane < OUT_C) ? expf(o - m) : 0.f;
    float s = e;
    #pragma unroll
    for (int off = 32; off; off >>= 1) s += __shfl_xor(s, off);
    if (lane < OUT_C) out[(size_t)node * OUT_C + lane] = o - m - logf(s);
}

extern "C" void kernel_launch(void* const* d_in, const int* in_sizes, int n_in,
                              void* d_out, int out_size, void* d_ws, size_t ws_size,
                              hipStream_t stream) {
    const float* x   = (const float*)d_in[0];
    const int*   ei  = (const int*)d_in[1];
    const float* Wl1 = (const float*)d_in[2];
    const float* bl1 = (const float*)d_in[3];
    const float* Wr1 = (const float*)d_in[4];
    const float* Wl2 = (const float*)d_in[5];
    const float* bl2 = (const float*)d_in[6];
    const float* Wr2 = (const float*)d_in[7];
    float* out = (float*)d_out;
    const int N = N_NODES;
    const int E = in_sizes[1] / 2;

    char* ws = (char*)d_ws;
    float* cnt = (float*)ws;                                  // [N] -> cmax after prep
    float* inv = (float*)(ws + 401408);                       // [N]
    float* B   = (float*)(ws + (1 << 20));                    // y1 [N][128] (later y2/agg2)
    float* C   = (float*)(ws + (1 << 20) + 51200000);         // agg1 / h [N][128]
    float* y2  = B;                                           // [N][40]
    float* ag2 = (float*)(ws + (1 << 20) + 16000000);         // [N][40]

    hipMemsetAsync(cnt, 0, (size_t)N * 4, stream);

    count_k<<<(E + 255) / 256, 256, 0, stream>>>(ei, E, cnt);
    prep_k<<<(N + 255) / 256, 256, 0, stream>>>(cnt, inv, N);

    // Layer 1: y1 = x@Wl1^T -> B ; agg1 init = (x@Wr1^T + bl1)*cmax -> C
    dim3 g1((N + TILE - 1) / TILE, (2 * HID) / TILE);
    gemm_split<<<g1, 256, 0, stream>>>(x, IN_C, Wl1, Wr1, bl1, cnt, B, C, HID, N);

    scatter128<<<(int)(((long long)E * 32 + 255) / 256), 256, 0, stream>>>(ei, E, B, C);
    relu_fin<<<(N * (HID / 4) + 255) / 256, 256, 0, stream>>>(C, inv, N * (HID / 4));

    // Layer 2: y2 = h@Wl2^T -> B ; agg2 init = (h@Wr2^T + bl2)*cmax -> ag2
    dim3 g2((N + TILE - 1) / TILE, (2 * OUT_C + TILE - 1) / TILE);
    gemm_split<<<g2, 256, 0, stream>>>(C, HID, Wl2, Wr2, bl2, cnt, y2, ag2, OUT_C, N);

    scatter40<<<(int)(((long long)E * 16 + 255) / 256), 256, 0, stream>>>(ei, E, y2, ag2);

    logsm_k<<<(N + 3) / 4, 256, 0, stream>>>(ag2, inv, out, N);
}

// Round 2
// 714.567 us; speedup vs baseline: 5.7068x; 5.7068x over previous
//
#include <hip/hip_runtime.h>
#include <hip/hip_bf16.h>

#define N_NODES 100000
#define IN_C 256
#define HID 128
#define OUT_C 40

constexpr int TILE = 64;
constexpr int KCH  = 64;
constexpr int TP   = TILE + 4;  // padded for [KCH][TP] layouts

static __device__ __forceinline__ float bf2f(unsigned short u) {
    return __uint_as_float(((unsigned)u) << 16);
}
static __device__ __forceinline__ unsigned short f2bf(float f) {
    unsigned u = __float_as_uint(f);
    u += 0x7fffu + ((u >> 16) & 1u);
    return (unsigned short)(u >> 16);
}

// ---------------- degree histogram (int) ----------------
__global__ __launch_bounds__(256) void count_k(const int* __restrict__ ei, int E, int* __restrict__ cnt) {
    int i = blockIdx.x * 256 + threadIdx.x;
    if (i >= E) return;
    int dst = ei[E + i];
    if ((unsigned)dst < (unsigned)N_NODES)
        atomicAdd(&cnt[dst], 1);
}

// ---------------- single-block exclusive scan + inv ----------------
__global__ __launch_bounds__(1024) void scan_k(const int* __restrict__ cnt, int* __restrict__ row_ptr,
                                               float* __restrict__ inv, int n) {
    __shared__ int wsum[16];
    __shared__ int carry_s;
    int tid = threadIdx.x, lane = tid & 63, wid = tid >> 6;
    if (tid == 0) carry_s = 0;
    __syncthreads();
    for (int base = 0; base < n; base += 1024) {
        int i = base + tid;
        int v = (i < n) ? cnt[i] : 0;
        int s = v;
        #pragma unroll
        for (int off = 1; off < 64; off <<= 1) {
            int t = __shfl_up(s, off);
            if (lane >= off) s += t;
        }
        if (lane == 63) wsum[wid] = s;
        __syncthreads();
        if (wid == 0 && lane < 16) {
            int w = wsum[lane];
            #pragma unroll
            for (int off = 1; off < 16; off <<= 1) {
                int t = __shfl_up(w, off, 16);
                if (lane >= off) w += t;
            }
            wsum[lane] = w;
        }
        __syncthreads();
        int carry = carry_s;
        if (i < n) {
            row_ptr[i] = carry + (wid ? wsum[wid - 1] : 0) + s - v;
            inv[i] = 1.0f / fmaxf((float)v, 1.0f);
        }
        __syncthreads();
        if (tid == 0) carry_s = carry + wsum[15];
        __syncthreads();
    }
    if (tid == 0) row_ptr[n] = carry_s;
}

// ---------------- CSR fill ----------------
__global__ __launch_bounds__(256) void fill_k(const int* __restrict__ ei, int E,
                                              int* __restrict__ cursor, int* __restrict__ csr) {
    int i = blockIdx.x * 256 + threadIdx.x;
    if (i >= E) return;
    int dst = ei[E + i];
    if ((unsigned)dst >= (unsigned)N_NODES) return;
    int pos = atomicAdd(&cursor[dst], 1);
    csr[pos] = ei[i];
}

// ---------------- fused GEMM: Y = X@Wl^T (bf16 or f32) ; Z = X@Wr^T + b ----------------
// X [nrows,K] row-major; Wl/Wr [half,K]; Y,Z [nrows,half]
template <bool YBF16>
__global__ __launch_bounds__(256) void gemm_split(
    const float* __restrict__ X, int K,
    const float* __restrict__ Wl, const float* __restrict__ Wr,
    const float* __restrict__ bias,
    void* __restrict__ Yv, float* __restrict__ Z,
    int half, int nrows)
{
    __shared__ float Xs[KCH][TP];   // k-major: Xs[k][row]
    __shared__ float Ws[KCH][TP];   // k-major: Ws[k][col]
    const int rowTile = blockIdx.x * TILE;
    const int colTile = blockIdx.y * TILE;
    const int tx = threadIdx.x;
    const int tc = tx & 15, tr = tx >> 4;
    const int ncols = 2 * half;
    float acc[4][4] = {};

    for (int k0 = 0; k0 < K; k0 += KCH) {
        #pragma unroll
        for (int i = 0; i < 4; ++i) {
            int idx = i * 256 + tx;
            int row = idx >> 4, kq = idx & 15;
            float4 v = make_float4(0.f, 0.f, 0.f, 0.f);
            int gr = rowTile + row;
            if (gr < nrows) v = *(const float4*)&X[(size_t)gr * K + k0 + kq * 4];
            Xs[kq*4+0][row] = v.x; Xs[kq*4+1][row] = v.y;
            Xs[kq*4+2][row] = v.z; Xs[kq*4+3][row] = v.w;
            float4 w = make_float4(0.f, 0.f, 0.f, 0.f);
            int wc = colTile + row;
            if (wc < ncols) {
                const float* Wp = (wc < half) ? &Wl[(size_t)wc * K] : &Wr[(size_t)(wc - half) * K];
                w = *(const float4*)&Wp[k0 + kq * 4];
            }
            Ws[kq*4+0][row] = w.x; Ws[kq*4+1][row] = w.y;
            Ws[kq*4+2][row] = w.z; Ws[kq*4+3][row] = w.w;
        }
        __syncthreads();
        #pragma unroll 8
        for (int k = 0; k < KCH; ++k) {
            float4 a = *(const float4*)&Xs[k][tr * 4];
            float4 b = *(const float4*)&Ws[k][tc * 4];
            acc[0][0] += a.x*b.x; acc[0][1] += a.x*b.y; acc[0][2] += a.x*b.z; acc[0][3] += a.x*b.w;
            acc[1][0] += a.y*b.x; acc[1][1] += a.y*b.y; acc[1][2] += a.y*b.z; acc[1][3] += a.y*b.w;
            acc[2][0] += a.z*b.x; acc[2][1] += a.z*b.y; acc[2][2] += a.z*b.z; acc[2][3] += a.z*b.w;
            acc[3][0] += a.w*b.x; acc[3][1] += a.w*b.y; acc[3][2] += a.w*b.z; acc[3][3] += a.w*b.w;
        }
        __syncthreads();
    }

    if (YBF16) {
        // tiles are column-uniform (TILE divides half)
        bool isY = (colTile < half);
        #pragma unroll
        for (int i = 0; i < 4; ++i) {
            int row = rowTile + tr * 4 + i;
            if (row >= nrows) continue;
            if (isY) {
                ushort4 o;
                o.x = f2bf(acc[i][0]); o.y = f2bf(acc[i][1]);
                o.z = f2bf(acc[i][2]); o.w = f2bf(acc[i][3]);
                *(ushort4*)&((unsigned short*)Yv)[(size_t)row * half + colTile + tc * 4] = o;
            } else {
                int c = colTile - half + tc * 4;
                float4 o;
                o.x = acc[i][0] + bias[c + 0]; o.y = acc[i][1] + bias[c + 1];
                o.z = acc[i][2] + bias[c + 2]; o.w = acc[i][3] + bias[c + 3];
                *(float4*)&Z[(size_t)row * half + c] = o;
            }
        }
    } else {
        float* Y = (float*)Yv;
        #pragma unroll
        for (int i = 0; i < 4; ++i) {
            int row = rowTile + tr * 4 + i;
            if (row >= nrows) continue;
            #pragma unroll
            for (int j = 0; j < 4; ++j) {
                int col = colTile + tc * 4 + j;
                if (col < half) {
                    Y[(size_t)row * half + col] = acc[i][j];
                } else if (col < ncols) {
                    int c = col - half;
                    Z[(size_t)row * half + c] = acc[i][j] + bias[c];
                }
            }
        }
    }
}

// ---------------- gather layer 1: h = relu(mean(Y[src]) + Z), in place over Z ----------------
__global__ __launch_bounds__(256) void gather1_k(const int* __restrict__ row_ptr, const int* __restrict__ csr,
                                                 const unsigned short* __restrict__ Y,
                                                 float* __restrict__ HZ, const float* __restrict__ inv, int n) {
    int node = blockIdx.x * 8 + (threadIdx.x >> 5);
    if (node >= n) return;
    int t = threadIdx.x & 31;
    int beg = row_ptr[node], end = row_ptr[node + 1];
    float ax = 0.f, ay = 0.f, az = 0.f, aw = 0.f;
    int e = beg;
    for (; e + 2 <= end; e += 2) {
        int s0 = csr[e], s1 = csr[e + 1];
        ushort4 v0 = *(const ushort4*)&Y[(size_t)s0 * HID + t * 4];
        ushort4 v1 = *(const ushort4*)&Y[(size_t)s1 * HID + t * 4];
        ax += bf2f(v0.x) + bf2f(v1.x);
        ay += bf2f(v0.y) + bf2f(v1.y);
        az += bf2f(v0.z) + bf2f(v1.z);
        aw += bf2f(v0.w) + bf2f(v1.w);
    }
    if (e < end) {
        int s0 = csr[e];
        ushort4 v0 = *(const ushort4*)&Y[(size_t)s0 * HID + t * 4];
        ax += bf2f(v0.x); ay += bf2f(v0.y); az += bf2f(v0.z); aw += bf2f(v0.w);
    }
    float iv = inv[node];
    float4 z = *(const float4*)&HZ[(size_t)node * HID + t * 4];
    float4 h;
    h.x = fmaxf(ax * iv + z.x, 0.f);
    h.y = fmaxf(ay * iv + z.y, 0.f);
    h.z = fmaxf(az * iv + z.z, 0.f);
    h.w = fmaxf(aw * iv + z.w, 0.f);
    *(float4*)&HZ[(size_t)node * HID + t * 4] = h;
}

// ---------------- gather layer 2 + log_softmax, writes d_out ----------------
__global__ __launch_bounds__(256) void gather2_logsm_k(const int* __restrict__ row_ptr, const int* __restrict__ csr,
                                                       const float* __restrict__ Y, const float* __restrict__ Z,
                                                       const float* __restrict__ inv,
                                                       float* __restrict__ out, int n) {
    int node = blockIdx.x * 16 + (threadIdx.x >> 4);
    if (node >= n) return;
    int t = threadIdx.x & 15;
    float4 v = make_float4(-INFINITY, -INFINITY, -INFINITY, -INFINITY);
    if (t < 10) {
        int beg = row_ptr[node], end = row_ptr[node + 1];
        float4 acc = make_float4(0.f, 0.f, 0.f, 0.f);
        for (int e = beg; e < end; ++e) {
            int s = csr[e];
            float4 y = *(const float4*)&Y[(size_t)s * OUT_C + t * 4];
            acc.x += y.x; acc.y += y.y; acc.z += y.z; acc.w += y.w;
        }
        float iv = inv[node];
        float4 z = *(const float4*)&Z[(size_t)node * OUT_C + t * 4];
        v.x = acc.x * iv + z.x; v.y = acc.y * iv + z.y;
        v.z = acc.z * iv + z.z; v.w = acc.w * iv + z.w;
    }
    float m = fmaxf(fmaxf(v.x, v.y), fmaxf(v.z, v.w));
    #pragma unroll
    for (int off = 8; off; off >>= 1) m = fmaxf(m, __shfl_xor(m, off, 16));
    float s4 = 0.f;
    if (t < 10) s4 = expf(v.x - m) + expf(v.y - m) + expf(v.z - m) + expf(v.w - m);
    #pragma unroll
    for (int off = 8; off; off >>= 1) s4 += __shfl_xor(s4, off, 16);
    float ls = m + logf(s4);
    if (t < 10) {
        float4 o;
        o.x = v.x - ls; o.y = v.y - ls; o.z = v.z - ls; o.w = v.w - ls;
        *(float4*)&out[(size_t)node * OUT_C + t * 4] = o;
    }
}

extern "C" void kernel_launch(void* const* d_in, const int* in_sizes, int n_in,
                              void* d_out, int out_size, void* d_ws, size_t ws_size,
                              hipStream_t stream) {
    const float* x   = (const float*)d_in[0];
    const int*   ei  = (const int*)d_in[1];
    const float* Wl1 = (const float*)d_in[2];
    const float* bl1 = (const float*)d_in[3];
    const float* Wr1 = (const float*)d_in[4];
    const float* Wl2 = (const float*)d_in[5];
    const float* bl2 = (const float*)d_in[6];
    const float* Wr2 = (const float*)d_in[7];
    float* out = (float*)d_out;
    const int N = N_NODES;
    const int E = in_sizes[1] / 2;

    char* ws = (char*)d_ws;
    int*   cnt_i   = (int*)(ws + 0x000000);              // [N]
    int*   row_ptr = (int*)(ws + 0x080000);              // [N+1]
    int*   cursor  = (int*)(ws + 0x100000);              // [N]
    float* inv     = (float*)(ws + 0x180000);            // [N]
    int*   csr     = (int*)(ws + 0x200000);              // [E] ends ~8.4MB
    unsigned short* Y1 = (unsigned short*)(ws + 0x1000000); // [N,128] bf16, 25.6MB (ends 41.6MB)
    float* Y2      = (float*)(ws + 0x1000000);           // [N,40] f32 (aliases Y1, used after gather1)
    float* Z2      = (float*)(ws + 0x2000000);           // [N,40] f32 (32MB..48MB)
    float* Z1      = (float*)(ws + 0x3000000);           // [N,128] f32 = h, 51.2MB (48MB..99.2MB)

    hipMemsetAsync(cnt_i, 0, (size_t)N * 4, stream);
    count_k<<<(E + 255) / 256, 256, 0, stream>>>(ei, E, cnt_i);
    scan_k<<<1, 1024, 0, stream>>>(cnt_i, row_ptr, inv, N);
    hipMemcpyAsync(cursor, row_ptr, (size_t)N * 4, hipMemcpyDeviceToDevice, stream);
    fill_k<<<(E + 255) / 256, 256, 0, stream>>>(ei, E, cursor, csr);

    // Layer 1: Y1 = bf16(x@Wl1^T) ; Z1 = x@Wr1^T + bl1
    dim3 g1((N + TILE - 1) / TILE, (2 * HID) / TILE);
    gemm_split<true><<<g1, 256, 0, stream>>>(x, IN_C, Wl1, Wr1, bl1, (void*)Y1, Z1, HID, N);

    // h = relu(mean + z) in place over Z1
    gather1_k<<<N / 8, 256, 0, stream>>>(row_ptr, csr, Y1, Z1, inv, N);

    // Layer 2: Y2 = h@Wl2^T ; Z2 = h@Wr2^T + bl2
    dim3 g2((N + TILE - 1) / TILE, (2 * OUT_C + TILE - 1) / TILE);
    gemm_split<false><<<g2, 256, 0, stream>>>(Z1, HID, Wl2, Wr2, bl2, (void*)Y2, Z2, OUT_C, N);

    // out = log_softmax(mean2 + z2)
    gather2_logsm_k<<<(N + 15) / 16, 256, 0, stream>>>(row_ptr, csr, Y2, Z2, inv, out, N);
}

// Round 3
// 544.436 us; speedup vs baseline: 7.4901x; 1.3125x over previous
//
#include <hip/hip_runtime.h>
#include <hip/hip_bf16.h>

#define N_NODES 100000
#define IN_C 256
#define HID 128
#define OUT_C 40

typedef short bf16x8 __attribute__((ext_vector_type(8)));
typedef float f32x4 __attribute__((ext_vector_type(4)));

static __device__ __forceinline__ float bf2f(unsigned short u) {
    return __uint_as_float(((unsigned)u) << 16);
}
static __device__ __forceinline__ unsigned short f2bf(float f) {
    unsigned u = __float_as_uint(f);
    u += 0x7fffu + ((u >> 16) & 1u);
    return (unsigned short)(u >> 16);
}

// ---------------- degree histogram (int) ----------------
__global__ __launch_bounds__(256) void count_k(const int* __restrict__ ei, int E, int* __restrict__ cnt) {
    int i = blockIdx.x * 256 + threadIdx.x;
    if (i >= E) return;
    int dst = ei[E + i];
    if ((unsigned)dst < (unsigned)N_NODES)
        atomicAdd(&cnt[dst], 1);
}

// ---------------- single-block exclusive scan + inv ----------------
__global__ __launch_bounds__(1024) void scan_k(const int* __restrict__ cnt, int* __restrict__ row_ptr,
                                               float* __restrict__ inv, int n) {
    __shared__ int wsum[16];
    __shared__ int carry_s;
    int tid = threadIdx.x, lane = tid & 63, wid = tid >> 6;
    if (tid == 0) carry_s = 0;
    __syncthreads();
    for (int base = 0; base < n; base += 1024) {
        int i = base + tid;
        int v = (i < n) ? cnt[i] : 0;
        int s = v;
        #pragma unroll
        for (int off = 1; off < 64; off <<= 1) {
            int t = __shfl_up(s, off);
            if (lane >= off) s += t;
        }
        if (lane == 63) wsum[wid] = s;
        __syncthreads();
        if (wid == 0 && lane < 16) {
            int w = wsum[lane];
            #pragma unroll
            for (int off = 1; off < 16; off <<= 1) {
                int t = __shfl_up(w, off, 16);
                if (lane >= off) w += t;
            }
            wsum[lane] = w;
        }
        __syncthreads();
        int carry = carry_s;
        if (i < n) {
            row_ptr[i] = carry + (wid ? wsum[wid - 1] : 0) + s - v;
            inv[i] = 1.0f / fmaxf((float)v, 1.0f);
        }
        __syncthreads();
        if (tid == 0) carry_s = carry + wsum[15];
        __syncthreads();
    }
    if (tid == 0) row_ptr[n] = carry_s;
}

// ---------------- CSR fill ----------------
__global__ __launch_bounds__(256) void fill_k(const int* __restrict__ ei, int E,
                                              int* __restrict__ cursor, int* __restrict__ csr) {
    int i = blockIdx.x * 256 + threadIdx.x;
    if (i >= E) return;
    int dst = ei[E + i];
    if ((unsigned)dst >= (unsigned)N_NODES) return;
    int pos = atomicAdd(&cursor[dst], 1);
    csr[pos] = ei[i];
}

// ---------------- f32 -> bf16 convert (n8 = n/8) ----------------
__global__ __launch_bounds__(256) void cvt_k(const float* __restrict__ src, unsigned short* __restrict__ dst, int n8) {
    int i = blockIdx.x * 256 + threadIdx.x;
    if (i >= n8) return;
    float4 v0 = *(const float4*)&src[(size_t)i * 8];
    float4 v1 = *(const float4*)&src[(size_t)i * 8 + 4];
    ushort4 o0, o1;
    o0.x = f2bf(v0.x); o0.y = f2bf(v0.y); o0.z = f2bf(v0.z); o0.w = f2bf(v0.w);
    o1.x = f2bf(v1.x); o1.y = f2bf(v1.y); o1.z = f2bf(v1.z); o1.w = f2bf(v1.w);
    *(ushort4*)&dst[(size_t)i * 8] = o0;
    *(ushort4*)&dst[(size_t)i * 8 + 4] = o1;
}

// ---------------- MFMA GEMM layer1: Y1=bf16(X@Wl^T) [y=0]; Z1b=bf16(X@Wr^T+b) [y=1] ----------------
// X [M,256] f32, Wb [256,256] bf16 (rows 0-127=Wl, 128-255=Wr)
__global__ __launch_bounds__(256) void gemm1_k(
    const float* __restrict__ X,
    const unsigned short* __restrict__ Wb,
    const float* __restrict__ bias,
    unsigned short* __restrict__ Y,
    unsigned short* __restrict__ Zb,
    int M)
{
    constexpr int LSTR = 72;  // 144B row stride: 16B-aligned, banks spread 4r%32 (2-way, free)
    __shared__ unsigned short As[128][LSTR];
    __shared__ unsigned short Bs[128][LSTR];
    const int tx = threadIdx.x;
    const int rowTile = blockIdx.x * 128;
    const int yhalf = blockIdx.y;
    const int wv = tx >> 6, ln = tx & 63;
    const int wr = wv >> 1, wc = wv & 1;
    const int lc = ln & 15, lk = (ln >> 4) * 8;
    f32x4 acc[4][4] = {};

    for (int k0 = 0; k0 < 256; k0 += 64) {
        #pragma unroll
        for (int i = 0; i < 4; ++i) {
            int idx = i * 256 + tx;
            int r = idx >> 3, kk = (idx & 7) * 8;
            int gr = rowTile + r;
            bf16x8 a = {};
            if (gr < M) {
                const float* p = &X[(size_t)gr * 256 + k0 + kk];
                float4 v0 = *(const float4*)p;
                float4 v1 = *(const float4*)(p + 4);
                a[0] = (short)f2bf(v0.x); a[1] = (short)f2bf(v0.y);
                a[2] = (short)f2bf(v0.z); a[3] = (short)f2bf(v0.w);
                a[4] = (short)f2bf(v1.x); a[5] = (short)f2bf(v1.y);
                a[6] = (short)f2bf(v1.z); a[7] = (short)f2bf(v1.w);
            }
            *(bf16x8*)&As[r][kk] = a;
            // W tile: bf16 direct 16B loads
            *(bf16x8*)&Bs[r][kk] = *(const bf16x8*)&Wb[(size_t)(yhalf * 128 + r) * 256 + k0 + kk];
        }
        __syncthreads();
        #pragma unroll
        for (int ks = 0; ks < 2; ++ks) {
            int koff = ks * 32 + lk;
            bf16x8 af[4], bfr[4];
            #pragma unroll
            for (int m = 0; m < 4; ++m) af[m] = *(bf16x8*)&As[wr * 64 + m * 16 + lc][koff];
            #pragma unroll
            for (int n = 0; n < 4; ++n) bfr[n] = *(bf16x8*)&Bs[wc * 64 + n * 16 + lc][koff];
            #pragma unroll
            for (int m = 0; m < 4; ++m)
                #pragma unroll
                for (int n = 0; n < 4; ++n)
                    acc[m][n] = __builtin_amdgcn_mfma_f32_16x16x32_bf16(af[m], bfr[n], acc[m][n], 0, 0, 0);
        }
        __syncthreads();
    }

    const int lr4 = (ln >> 4) * 4;
    #pragma unroll
    for (int m = 0; m < 4; ++m) {
        int gr0 = rowTile + wr * 64 + m * 16 + lr4;
        #pragma unroll
        for (int n = 0; n < 4; ++n) {
            int col = wc * 64 + n * 16 + lc;
            float b = (yhalf == 1) ? bias[col] : 0.f;
            #pragma unroll
            for (int j = 0; j < 4; ++j) {
                int gr = gr0 + j;
                if (gr >= M) continue;
                float v = acc[m][n][j];
                if (yhalf == 0) Y[(size_t)gr * 128 + col] = f2bf(v);
                else            Zb[(size_t)gr * 128 + col] = f2bf(v + b);
            }
        }
    }
}

// ---------------- MFMA GEMM layer2: cols 0-39 -> Y2 bf16 (h@Wl2^T), 40-79 -> Z2 f32 (h@Wr2^T+b) ----
// Hb [M,128] bf16, Wb [80,128] bf16 (rows 0-39=Wl2, 40-79=Wr2)
__global__ __launch_bounds__(256) void gemm2_k(
    const unsigned short* __restrict__ Hb,
    const unsigned short* __restrict__ Wb,
    const float* __restrict__ bias,
    unsigned short* __restrict__ Y2,
    float* __restrict__ Z2,
    int M)
{
    constexpr int LSTR = 72;
    __shared__ unsigned short As[128][LSTR];
    __shared__ unsigned short Bs[80][LSTR];
    const int tx = threadIdx.x;
    const int rowTile = blockIdx.x * 128;
    const int wv = tx >> 6, ln = tx & 63;
    const int lc = ln & 15, lk = (ln >> 4) * 8;
    f32x4 acc[2][5] = {};

    for (int k0 = 0; k0 < 128; k0 += 64) {
        #pragma unroll
        for (int i = 0; i < 4; ++i) {
            int idx = i * 256 + tx;
            int r = idx >> 3, kk = (idx & 7) * 8;
            int gr = rowTile + r;
            bf16x8 a = {};
            if (gr < M) a = *(const bf16x8*)&Hb[(size_t)gr * 128 + k0 + kk];
            *(bf16x8*)&As[r][kk] = a;
        }
        #pragma unroll
        for (int i = 0; i < 3; ++i) {
            int idx = i * 256 + tx;
            if (idx < 640) {
                int c = idx >> 3, kk = (idx & 7) * 8;
                *(bf16x8*)&Bs[c][kk] = *(const bf16x8*)&Wb[(size_t)c * 128 + k0 + kk];
            }
        }
        __syncthreads();
        #pragma unroll
        for (int ks = 0; ks < 2; ++ks) {
            int koff = ks * 32 + lk;
            bf16x8 af[2], bfr[5];
            #pragma unroll
            for (int m = 0; m < 2; ++m) af[m] = *(bf16x8*)&As[wv * 32 + m * 16 + lc][koff];
            #pragma unroll
            for (int n = 0; n < 5; ++n) bfr[n] = *(bf16x8*)&Bs[n * 16 + lc][koff];
            #pragma unroll
            for (int m = 0; m < 2; ++m)
                #pragma unroll
                for (int n = 0; n < 5; ++n)
                    acc[m][n] = __builtin_amdgcn_mfma_f32_16x16x32_bf16(af[m], bfr[n], acc[m][n], 0, 0, 0);
        }
        __syncthreads();
    }

    const int lr4 = (ln >> 4) * 4;
    #pragma unroll
    for (int m = 0; m < 2; ++m) {
        int gr0 = rowTile + wv * 32 + m * 16 + lr4;
        #pragma unroll
        for (int n = 0; n < 5; ++n) {
            int col = n * 16 + lc;
            #pragma unroll
            for (int j = 0; j < 4; ++j) {
                int gr = gr0 + j;
                if (gr >= M) continue;
                float v = acc[m][n][j];
                if (col < 40) Y2[(size_t)gr * 40 + col] = f2bf(v);
                else          Z2[(size_t)gr * 40 + (col - 40)] = v + bias[col - 40];
            }
        }
    }
}

// ---------------- gather layer 1: h = bf16(relu(mean(Y[src]) + Z)), in place over Zb ----------------
__global__ __launch_bounds__(256) void gather1_k(const int* __restrict__ row_ptr, const int* __restrict__ csr,
                                                 const unsigned short* __restrict__ Y,
                                                 unsigned short* __restrict__ Zb,
                                                 const float* __restrict__ inv, int n) {
    int node = blockIdx.x * 8 + (threadIdx.x >> 5);
    if (node >= n) return;
    int t = threadIdx.x & 31;
    int beg = row_ptr[node], end = row_ptr[node + 1];
    float a0 = 0.f, a1 = 0.f, a2 = 0.f, a3 = 0.f;
    int e = beg;
    for (; e + 2 <= end; e += 2) {
        int s0 = csr[e], s1 = csr[e + 1];
        ushort4 v0 = *(const ushort4*)&Y[(size_t)s0 * HID + t * 4];
        ushort4 v1 = *(const ushort4*)&Y[(size_t)s1 * HID + t * 4];
        a0 += bf2f(v0.x) + bf2f(v1.x);
        a1 += bf2f(v0.y) + bf2f(v1.y);
        a2 += bf2f(v0.z) + bf2f(v1.z);
        a3 += bf2f(v0.w) + bf2f(v1.w);
    }
    if (e < end) {
        int s0 = csr[e];
        ushort4 v0 = *(const ushort4*)&Y[(size_t)s0 * HID + t * 4];
        a0 += bf2f(v0.x); a1 += bf2f(v0.y); a2 += bf2f(v0.z); a3 += bf2f(v0.w);
    }
    float iv = inv[node];
    ushort4 z = *(const ushort4*)&Zb[(size_t)node * HID + t * 4];
    ushort4 h;
    h.x = f2bf(fmaxf(a0 * iv + bf2f(z.x), 0.f));
    h.y = f2bf(fmaxf(a1 * iv + bf2f(z.y), 0.f));
    h.z = f2bf(fmaxf(a2 * iv + bf2f(z.z), 0.f));
    h.w = f2bf(fmaxf(a3 * iv + bf2f(z.w), 0.f));
    *(ushort4*)&Zb[(size_t)node * HID + t * 4] = h;
}

// ---------------- gather layer 2 + log_softmax, writes d_out ----------------
__global__ __launch_bounds__(256) void gather2_logsm_k(const int* __restrict__ row_ptr, const int* __restrict__ csr,
                                                       const unsigned short* __restrict__ Y, const float* __restrict__ Z,
                                                       const float* __restrict__ inv,
                                                       float* __restrict__ out, int n) {
    int node = blockIdx.x * 16 + (threadIdx.x >> 4);
    if (node >= n) return;
    int t = threadIdx.x & 15;
    float4 v = make_float4(-INFINITY, -INFINITY, -INFINITY, -INFINITY);
    if (t < 10) {
        int beg = row_ptr[node], end = row_ptr[node + 1];
        float4 acc = make_float4(0.f, 0.f, 0.f, 0.f);
        for (int e = beg; e < end; ++e) {
            int s = csr[e];
            ushort4 y = *(const ushort4*)&Y[(size_t)s * OUT_C + t * 4];
            acc.x += bf2f(y.x); acc.y += bf2f(y.y); acc.z += bf2f(y.z); acc.w += bf2f(y.w);
        }
        float iv = inv[node];
        float4 z = *(const float4*)&Z[(size_t)node * OUT_C + t * 4];
        v.x = acc.x * iv + z.x; v.y = acc.y * iv + z.y;
        v.z = acc.z * iv + z.z; v.w = acc.w * iv + z.w;
    }
    float m = fmaxf(fmaxf(v.x, v.y), fmaxf(v.z, v.w));
    #pragma unroll
    for (int off = 8; off; off >>= 1) m = fmaxf(m, __shfl_xor(m, off, 16));
    float s4 = 0.f;
    if (t < 10) s4 = expf(v.x - m) + expf(v.y - m) + expf(v.z - m) + expf(v.w - m);
    #pragma unroll
    for (int off = 8; off; off >>= 1) s4 += __shfl_xor(s4, off, 16);
    float ls = m + logf(s4);
    if (t < 10) {
        float4 o;
        o.x = v.x - ls; o.y = v.y - ls; o.z = v.z - ls; o.w = v.w - ls;
        *(float4*)&out[(size_t)node * OUT_C + t * 4] = o;
    }
}

extern "C" void kernel_launch(void* const* d_in, const int* in_sizes, int n_in,
                              void* d_out, int out_size, void* d_ws, size_t ws_size,
                              hipStream_t stream) {
    const float* x   = (const float*)d_in[0];
    const int*   ei  = (const int*)d_in[1];
    const float* Wl1 = (const float*)d_in[2];
    const float* bl1 = (const float*)d_in[3];
    const float* Wr1 = (const float*)d_in[4];
    const float* Wl2 = (const float*)d_in[5];
    const float* bl2 = (const float*)d_in[6];
    const float* Wr2 = (const float*)d_in[7];
    float* out = (float*)d_out;
    const int N = N_NODES;
    const int E = in_sizes[1] / 2;

    char* ws = (char*)d_ws;
    int*   cnt_i   = (int*)(ws + 0x000000);                 // [N]
    int*   row_ptr = (int*)(ws + 0x080000);                 // [N+1]
    int*   cursor  = (int*)(ws + 0x100000);                 // [N]
    float* inv     = (float*)(ws + 0x180000);               // [N]
    int*   csr     = (int*)(ws + 0x200000);                 // [E] -> ends ~8.6MB
    unsigned short* W1b = (unsigned short*)(ws + 0x830000); // [256*256] bf16, 128KB
    unsigned short* W2b = (unsigned short*)(ws + 0x850000); // [80*128] bf16, 20KB
    unsigned short* Y1  = (unsigned short*)(ws + 0x900000);  // [N,128] bf16, 25.6MB
    unsigned short* Z1b = (unsigned short*)(ws + 0x2200000); // [N,128] bf16 -> h in place
    unsigned short* Y2  = (unsigned short*)(ws + 0x3B00000); // [N,40] bf16, 8MB
    float* Z2           = (float*)(ws + 0x4300000);          // [N,40] f32, 16MB -> ends ~86MB

    hipMemsetAsync(cnt_i, 0, (size_t)N * 4, stream);
    count_k<<<(E + 255) / 256, 256, 0, stream>>>(ei, E, cnt_i);
    scan_k<<<1, 1024, 0, stream>>>(cnt_i, row_ptr, inv, N);
    hipMemcpyAsync(cursor, row_ptr, (size_t)N * 4, hipMemcpyDeviceToDevice, stream);
    fill_k<<<(E + 255) / 256, 256, 0, stream>>>(ei, E, cursor, csr);

    // weight conversions
    cvt_k<<<16, 256, 0, stream>>>(Wl1, W1b, 4096);
    cvt_k<<<16, 256, 0, stream>>>(Wr1, W1b + 32768, 4096);
    cvt_k<<<3, 256, 0, stream>>>(Wl2, W2b, 640);
    cvt_k<<<3, 256, 0, stream>>>(Wr2, W2b + 5120, 640);

    // Layer 1 (MFMA): y=0 -> Y1, y=1 -> Z1b
    dim3 g1((N + 127) / 128, 2);
    gemm1_k<<<g1, 256, 0, stream>>>(x, W1b, bl1, Y1, Z1b, N);

    // h = bf16(relu(mean + z)) in place over Z1b
    gather1_k<<<N / 8, 256, 0, stream>>>(row_ptr, csr, Y1, Z1b, inv, N);

    // Layer 2 (MFMA): Y2 bf16, Z2 f32+bias
    gemm2_k<<<(N + 127) / 128, 256, 0, stream>>>(Z1b, W2b, bl2, Y2, Z2, N);

    // out = log_softmax(mean2 + z2)
    gather2_logsm_k<<<(N + 15) / 16, 256, 0, stream>>>(row_ptr, csr, Y2, Z2, inv, out, N);
}

// Round 4
// 295.061 us; speedup vs baseline: 13.8205x; 1.8452x over previous
//
#include <hip/hip_runtime.h>
#include <hip/hip_bf16.h>

#define N_NODES 100000
#define IN_C 256
#define HID 128
#define OUT_C 40

#define NPB 9
#define NPP (1 << NPB)                          // 512 nodes per partition
#define NPART ((N_NODES + NPP - 1) >> NPB)      // 196

typedef short bf16x8 __attribute__((ext_vector_type(8)));
typedef float f32x4 __attribute__((ext_vector_type(4)));

static __device__ __forceinline__ float bf2f(unsigned short u) {
    return __uint_as_float(((unsigned)u) << 16);
}
static __device__ __forceinline__ unsigned short f2bf(float f) {
    unsigned u = __float_as_uint(f);
    u += 0x7fffu + ((u >> 16) & 1u);
    return (unsigned short)(u >> 16);
}

// ---------------- A0: partition histogram ----------------
__global__ __launch_bounds__(256) void phist_k(const int* __restrict__ ei, int E, int* __restrict__ pcnt) {
    __shared__ int lh[NPART];
    int tid = threadIdx.x;
    if (tid < NPART) lh[tid] = 0;
    __syncthreads();
    int base = blockIdx.x * 4096;
    int n = min(4096, E - base);
    for (int i = tid; i < n; i += 256)
        atomicAdd(&lh[((unsigned)ei[E + base + i]) >> NPB], 1);
    __syncthreads();
    if (tid < NPART) {
        int c = lh[tid];
        if (c) atomicAdd(&pcnt[tid], c);
    }
}

// ---------------- A1: scan partition counts ----------------
__global__ __launch_bounds__(256) void pscan_k(const int* __restrict__ pcnt, int* __restrict__ pbase,
                                               int* __restrict__ pcur) {
    __shared__ int wsum[4];
    int t = threadIdx.x, lane = t & 63, w = t >> 6;
    int v = (t < NPART) ? pcnt[t] : 0;
    int s = v;
    #pragma unroll
    for (int off = 1; off < 64; off <<= 1) { int x = __shfl_up(s, off); if (lane >= off) s += x; }
    if (lane == 63) wsum[w] = s;
    __syncthreads();
    int woff = 0;
    for (int i = 0; i < w; ++i) woff += wsum[i];
    int excl = woff + s - v;
    if (t < NPART) { pbase[t] = excl; pcur[t] = excl; }
    if (t == 255) pbase[NPART] = woff + s;   // total = E
}

// ---------------- A2: scatter edges into partition-grouped pairs ----------------
__global__ __launch_bounds__(256) void pscatter_k(const int* __restrict__ ei, int E,
                                                  int* __restrict__ pcur, int2* __restrict__ pairs) {
    __shared__ int lh[NPART];
    __shared__ int lb[NPART];
    int tid = threadIdx.x;
    if (tid < NPART) lh[tid] = 0;
    __syncthreads();
    int base = blockIdx.x * 4096;
    int n = min(4096, E - base);
    for (int i = tid; i < n; i += 256)
        atomicAdd(&lh[((unsigned)ei[E + base + i]) >> NPB], 1);
    __syncthreads();
    if (tid < NPART) {
        int c = lh[tid];
        lb[tid] = c ? atomicAdd(&pcur[tid], c) : 0;
        lh[tid] = 0;
    }
    __syncthreads();
    for (int i = tid; i < n; i += 256) {
        int src = ei[base + i];
        int dst = ei[E + base + i];
        int p = ((unsigned)dst) >> NPB;
        int r = atomicAdd(&lh[p], 1);
        pairs[lb[p] + r] = make_int2(src, dst);
    }
}

// ---------------- B: per-partition CSR build (LDS count+scan+fill) ----------------
__global__ __launch_bounds__(256) void pbuild_k(const int2* __restrict__ pairs, const int* __restrict__ pbase,
                                                int* __restrict__ row_ptr, float* __restrict__ inv,
                                                int* __restrict__ csr, int N) {
    __shared__ int cnt[NPP];
    __shared__ int cur[NPP];
    __shared__ int wsum[4];
    int p = blockIdx.x;
    int ebeg = pbase[p], eend = pbase[p + 1];
    int node0 = p << NPB;
    int tid = threadIdx.x;
    cnt[2 * tid] = 0; cnt[2 * tid + 1] = 0;
    __syncthreads();
    for (int e = ebeg + tid; e < eend; e += 256)
        atomicAdd(&cnt[pairs[e].y - node0], 1);
    __syncthreads();
    // scan 512 counts: thread t owns elements 2t, 2t+1
    int c0 = cnt[2 * tid], c1 = cnt[2 * tid + 1];
    int s = c0 + c1;
    int lane = tid & 63, w = tid >> 6;
    int ps = s;
    #pragma unroll
    for (int off = 1; off < 64; off <<= 1) { int x = __shfl_up(ps, off); if (lane >= off) ps += x; }
    if (lane == 63) wsum[w] = ps;
    __syncthreads();
    int woff = 0;
    for (int i = 0; i < w; ++i) woff += wsum[i];
    int excl = woff + ps - s;
    int node = node0 + 2 * tid;
    if (node < N)     { row_ptr[node]     = ebeg + excl;      inv[node]     = 1.f / fmaxf((float)c0, 1.f); }
    if (node + 1 < N) { row_ptr[node + 1] = ebeg + excl + c0; inv[node + 1] = 1.f / fmaxf((float)c1, 1.f); }
    cur[2 * tid] = excl; cur[2 * tid + 1] = excl + c0;
    if (p == NPART - 1 && tid == 255) row_ptr[N] = eend;
    __syncthreads();
    for (int e = ebeg + tid; e < eend; e += 256) {
        int2 pr = pairs[e];
        int r = atomicAdd(&cur[pr.y - node0], 1);
        csr[ebeg + r] = pr.x;
    }
}

// ---------------- f32 -> bf16 convert (n8 = n/8) ----------------
__global__ __launch_bounds__(256) void cvt_k(const float* __restrict__ src, unsigned short* __restrict__ dst, int n8) {
    int i = blockIdx.x * 256 + threadIdx.x;
    if (i >= n8) return;
    float4 v0 = *(const float4*)&src[(size_t)i * 8];
    float4 v1 = *(const float4*)&src[(size_t)i * 8 + 4];
    ushort4 o0, o1;
    o0.x = f2bf(v0.x); o0.y = f2bf(v0.y); o0.z = f2bf(v0.z); o0.w = f2bf(v0.w);
    o1.x = f2bf(v1.x); o1.y = f2bf(v1.y); o1.z = f2bf(v1.z); o1.w = f2bf(v1.w);
    *(ushort4*)&dst[(size_t)i * 8] = o0;
    *(ushort4*)&dst[(size_t)i * 8 + 4] = o1;
}

// ---------------- MFMA GEMM layer1: Y1=bf16(X@Wl^T) [y=0]; Z1b=bf16(X@Wr^T+b) [y=1] ----------------
__global__ __launch_bounds__(256) void gemm1_k(
    const float* __restrict__ X,
    const unsigned short* __restrict__ Wb,
    const float* __restrict__ bias,
    unsigned short* __restrict__ Y,
    unsigned short* __restrict__ Zb,
    int M)
{
    constexpr int LSTR = 72;
    __shared__ unsigned short As[128][LSTR];
    __shared__ unsigned short Bs[128][LSTR];
    const int tx = threadIdx.x;
    const int rowTile = blockIdx.x * 128;
    const int yhalf = blockIdx.y;
    const int wv = tx >> 6, ln = tx & 63;
    const int wr = wv >> 1, wc = wv & 1;
    const int lc = ln & 15, lk = (ln >> 4) * 8;
    f32x4 acc[4][4] = {};

    for (int k0 = 0; k0 < 256; k0 += 64) {
        #pragma unroll
        for (int i = 0; i < 4; ++i) {
            int idx = i * 256 + tx;
            int r = idx >> 3, kk = (idx & 7) * 8;
            int gr = rowTile + r;
            bf16x8 a = {};
            if (gr < M) {
                const float* p = &X[(size_t)gr * 256 + k0 + kk];
                float4 v0 = *(const float4*)p;
                float4 v1 = *(const float4*)(p + 4);
                a[0] = (short)f2bf(v0.x); a[1] = (short)f2bf(v0.y);
                a[2] = (short)f2bf(v0.z); a[3] = (short)f2bf(v0.w);
                a[4] = (short)f2bf(v1.x); a[5] = (short)f2bf(v1.y);
                a[6] = (short)f2bf(v1.z); a[7] = (short)f2bf(v1.w);
            }
            *(bf16x8*)&As[r][kk] = a;
            *(bf16x8*)&Bs[r][kk] = *(const bf16x8*)&Wb[(size_t)(yhalf * 128 + r) * 256 + k0 + kk];
        }
        __syncthreads();
        #pragma unroll
        for (int ks = 0; ks < 2; ++ks) {
            int koff = ks * 32 + lk;
            bf16x8 af[4], bfr[4];
            #pragma unroll
            for (int m = 0; m < 4; ++m) af[m] = *(bf16x8*)&As[wr * 64 + m * 16 + lc][koff];
            #pragma unroll
            for (int n = 0; n < 4; ++n) bfr[n] = *(bf16x8*)&Bs[wc * 64 + n * 16 + lc][koff];
            #pragma unroll
            for (int m = 0; m < 4; ++m)
                #pragma unroll
                for (int n = 0; n < 4; ++n)
                    acc[m][n] = __builtin_amdgcn_mfma_f32_16x16x32_bf16(af[m], bfr[n], acc[m][n], 0, 0, 0);
        }
        __syncthreads();
    }

    const int lr4 = (ln >> 4) * 4;
    #pragma unroll
    for (int m = 0; m < 4; ++m) {
        int gr0 = rowTile + wr * 64 + m * 16 + lr4;
        #pragma unroll
        for (int n = 0; n < 4; ++n) {
            int col = wc * 64 + n * 16 + lc;
            float b = (yhalf == 1) ? bias[col] : 0.f;
            #pragma unroll
            for (int j = 0; j < 4; ++j) {
                int gr = gr0 + j;
                if (gr >= M) continue;
                float v = acc[m][n][j];
                if (yhalf == 0) Y[(size_t)gr * 128 + col] = f2bf(v);
                else            Zb[(size_t)gr * 128 + col] = f2bf(v + b);
            }
        }
    }
}

// ---------------- MFMA GEMM layer2 ----------------
__global__ __launch_bounds__(256) void gemm2_k(
    const unsigned short* __restrict__ Hb,
    const unsigned short* __restrict__ Wb,
    const float* __restrict__ bias,
    unsigned short* __restrict__ Y2,
    float* __restrict__ Z2,
    int M)
{
    constexpr int LSTR = 72;
    __shared__ unsigned short As[128][LSTR];
    __shared__ unsigned short Bs[80][LSTR];
    const int tx = threadIdx.x;
    const int rowTile = blockIdx.x * 128;
    const int wv = tx >> 6, ln = tx & 63;
    const int lc = ln & 15, lk = (ln >> 4) * 8;
    f32x4 acc[2][5] = {};

    for (int k0 = 0; k0 < 128; k0 += 64) {
        #pragma unroll
        for (int i = 0; i < 4; ++i) {
            int idx = i * 256 + tx;
            int r = idx >> 3, kk = (idx & 7) * 8;
            int gr = rowTile + r;
            bf16x8 a = {};
            if (gr < M) a = *(const bf16x8*)&Hb[(size_t)gr * 128 + k0 + kk];
            *(bf16x8*)&As[r][kk] = a;
        }
        #pragma unroll
        for (int i = 0; i < 3; ++i) {
            int idx = i * 256 + tx;
            if (idx < 640) {
                int c = idx >> 3, kk = (idx & 7) * 8;
                *(bf16x8*)&Bs[c][kk] = *(const bf16x8*)&Wb[(size_t)c * 128 + k0 + kk];
            }
        }
        __syncthreads();
        #pragma unroll
        for (int ks = 0; ks < 2; ++ks) {
            int koff = ks * 32 + lk;
            bf16x8 af[2], bfr[5];
            #pragma unroll
            for (int m = 0; m < 2; ++m) af[m] = *(bf16x8*)&As[wv * 32 + m * 16 + lc][koff];
            #pragma unroll
            for (int n = 0; n < 5; ++n) bfr[n] = *(bf16x8*)&Bs[n * 16 + lc][koff];
            #pragma unroll
            for (int m = 0; m < 2; ++m)
                #pragma unroll
                for (int n = 0; n < 5; ++n)
                    acc[m][n] = __builtin_amdgcn_mfma_f32_16x16x32_bf16(af[m], bfr[n], acc[m][n], 0, 0, 0);
        }
        __syncthreads();
    }

    const int lr4 = (ln >> 4) * 4;
    #pragma unroll
    for (int m = 0; m < 2; ++m) {
        int gr0 = rowTile + wv * 32 + m * 16 + lr4;
        #pragma unroll
        for (int n = 0; n < 5; ++n) {
            int col = n * 16 + lc;
            #pragma unroll
            for (int j = 0; j < 4; ++j) {
                int gr = gr0 + j;
                if (gr >= M) continue;
                float v = acc[m][n][j];
                if (col < 40) Y2[(size_t)gr * 40 + col] = f2bf(v);
                else          Z2[(size_t)gr * 40 + (col - 40)] = v + bias[col - 40];
            }
        }
    }
}

// ---------------- gather layer 1: h = bf16(relu(mean(Y[src]) + Z)), in place over Zb ----------------
__global__ __launch_bounds__(256) void gather1_k(const int* __restrict__ row_ptr, const int* __restrict__ csr,
                                                 const unsigned short* __restrict__ Y,
                                                 unsigned short* __restrict__ Zb,
                                                 const float* __restrict__ inv, int n) {
    int node = blockIdx.x * 8 + (threadIdx.x >> 5);
    if (node >= n) return;
    int t = threadIdx.x & 31;
    int beg = row_ptr[node], end = row_ptr[node + 1];
    float a0 = 0.f, a1 = 0.f, a2 = 0.f, a3 = 0.f;
    int e = beg;
    for (; e + 4 <= end; e += 4) {
        int s0 = csr[e], s1 = csr[e + 1], s2 = csr[e + 2], s3 = csr[e + 3];
        ushort4 v0 = *(const ushort4*)&Y[(size_t)s0 * HID + t * 4];
        ushort4 v1 = *(const ushort4*)&Y[(size_t)s1 * HID + t * 4];
        ushort4 v2 = *(const ushort4*)&Y[(size_t)s2 * HID + t * 4];
        ushort4 v3 = *(const ushort4*)&Y[(size_t)s3 * HID + t * 4];
        a0 += bf2f(v0.x) + bf2f(v1.x) + bf2f(v2.x) + bf2f(v3.x);
        a1 += bf2f(v0.y) + bf2f(v1.y) + bf2f(v2.y) + bf2f(v3.y);
        a2 += bf2f(v0.z) + bf2f(v1.z) + bf2f(v2.z) + bf2f(v3.z);
        a3 += bf2f(v0.w) + bf2f(v1.w) + bf2f(v2.w) + bf2f(v3.w);
    }
    for (; e < end; ++e) {
        int s0 = csr[e];
        ushort4 v0 = *(const ushort4*)&Y[(size_t)s0 * HID + t * 4];
        a0 += bf2f(v0.x); a1 += bf2f(v0.y); a2 += bf2f(v0.z); a3 += bf2f(v0.w);
    }
    float iv = inv[node];
    ushort4 z = *(const ushort4*)&Zb[(size_t)node * HID + t * 4];
    ushort4 h;
    h.x = f2bf(fmaxf(a0 * iv + bf2f(z.x), 0.f));
    h.y = f2bf(fmaxf(a1 * iv + bf2f(z.y), 0.f));
    h.z = f2bf(fmaxf(a2 * iv + bf2f(z.z), 0.f));
    h.w = f2bf(fmaxf(a3 * iv + bf2f(z.w), 0.f));
    *(ushort4*)&Zb[(size_t)node * HID + t * 4] = h;
}

// ---------------- gather layer 2 + log_softmax ----------------
__global__ __launch_bounds__(256) void gather2_logsm_k(const int* __restrict__ row_ptr, const int* __restrict__ csr,
                                                       const unsigned short* __restrict__ Y, const float* __restrict__ Z,
                                                       const float* __restrict__ inv,
                                                       float* __restrict__ out, int n) {
    int node = blockIdx.x * 16 + (threadIdx.x >> 4);
    if (node >= n) return;
    int t = threadIdx.x & 15;
    float4 v = make_float4(-INFINITY, -INFINITY, -INFINITY, -INFINITY);
    if (t < 10) {
        int beg = row_ptr[node], end = row_ptr[node + 1];
        float4 acc = make_float4(0.f, 0.f, 0.f, 0.f);
        for (int e = beg; e < end; ++e) {
            int s = csr[e];
            ushort4 y = *(const ushort4*)&Y[(size_t)s * OUT_C + t * 4];
            acc.x += bf2f(y.x); acc.y += bf2f(y.y); acc.z += bf2f(y.z); acc.w += bf2f(y.w);
        }
        float iv = inv[node];
        float4 z = *(const float4*)&Z[(size_t)node * OUT_C + t * 4];
        v.x = acc.x * iv + z.x; v.y = acc.y * iv + z.y;
        v.z = acc.z * iv + z.z; v.w = acc.w * iv + z.w;
    }
    float m = fmaxf(fmaxf(v.x, v.y), fmaxf(v.z, v.w));
    #pragma unroll
    for (int off = 8; off; off >>= 1) m = fmaxf(m, __shfl_xor(m, off, 16));
    float s4 = 0.f;
    if (t < 10) s4 = expf(v.x - m) + expf(v.y - m) + expf(v.z - m) + expf(v.w - m);
    #pragma unroll
    for (int off = 8; off; off >>= 1) s4 += __shfl_xor(s4, off, 16);
    float ls = m + logf(s4);
    if (t < 10) {
        float4 o;
        o.x = v.x - ls; o.y = v.y - ls; o.z = v.z - ls; o.w = v.w - ls;
        *(float4*)&out[(size_t)node * OUT_C + t * 4] = o;
    }
}

extern "C" void kernel_launch(void* const* d_in, const int* in_sizes, int n_in,
                              void* d_out, int out_size, void* d_ws, size_t ws_size,
                              hipStream_t stream) {
    const float* x   = (const float*)d_in[0];
    const int*   ei  = (const int*)d_in[1];
    const float* Wl1 = (const float*)d_in[2];
    const float* bl1 = (const float*)d_in[3];
    const float* Wr1 = (const float*)d_in[4];
    const float* Wl2 = (const float*)d_in[5];
    const float* bl2 = (const float*)d_in[6];
    const float* Wr2 = (const float*)d_in[7];
    float* out = (float*)d_out;
    const int N = N_NODES;
    const int E = in_sizes[1] / 2;

    char* ws = (char*)d_ws;
    int*   pcnt    = (int*)(ws + 0x0000);                   // [NPART]
    int*   pbase   = (int*)(ws + 0x1000);                   // [NPART+1]
    int*   pcur    = (int*)(ws + 0x2000);                   // [NPART]
    int*   row_ptr = (int*)(ws + 0x10000);                  // [N+1]  (ends ~0.46MB)
    float* inv     = (float*)(ws + 0x80000);                // [N]    (ends ~0.92MB)
    int*   csr     = (int*)(ws + 0x100000);                 // [E] 6.4MB (1MB..7.4MB)
    int2*  pairs   = (int2*)(ws + 0x800000);                // [E] 12.8MB (8.4..21.2MB), dead after pbuild
    float* Z2      = (float*)(ws + 0x800000);               // [N,40] f32 16MB, aliases pairs (8.4..24.4MB)
    unsigned short* W1b = (unsigned short*)(ws + 0x1900000);// 128KB (26.2MB)
    unsigned short* W2b = (unsigned short*)(ws + 0x1930000);// 20KB
    unsigned short* Y1  = (unsigned short*)(ws + 0x1A00000);// [N,128] bf16 25.6MB (27.3..52.9MB)
    unsigned short* Z1b = (unsigned short*)(ws + 0x3500000);// [N,128] bf16 25.6MB (55.6..81.2MB)
    unsigned short* Y2  = (unsigned short*)(ws + 0x5200000);// [N,40] bf16 8MB (86..94MB)

    // ---- CSR build: partitioned counting sort ----
    hipMemsetAsync(pcnt, 0, NPART * 4, stream);
    int nblk = (E + 4095) / 4096;
    phist_k<<<nblk, 256, 0, stream>>>(ei, E, pcnt);
    pscan_k<<<1, 256, 0, stream>>>(pcnt, pbase, pcur);
    pscatter_k<<<nblk, 256, 0, stream>>>(ei, E, pcur, pairs);
    pbuild_k<<<NPART, 256, 0, stream>>>(pairs, pbase, row_ptr, inv, csr, N);

    // ---- weight conversions ----
    cvt_k<<<16, 256, 0, stream>>>(Wl1, W1b, 4096);
    cvt_k<<<16, 256, 0, stream>>>(Wr1, W1b + 32768, 4096);
    cvt_k<<<3, 256, 0, stream>>>(Wl2, W2b, 640);
    cvt_k<<<3, 256, 0, stream>>>(Wr2, W2b + 5120, 640);

    // ---- Layer 1 (MFMA): y=0 -> Y1, y=1 -> Z1b ----
    dim3 g1((N + 127) / 128, 2);
    gemm1_k<<<g1, 256, 0, stream>>>(x, W1b, bl1, Y1, Z1b, N);

    // ---- h = bf16(relu(mean + z)) in place over Z1b ----
    gather1_k<<<N / 8, 256, 0, stream>>>(row_ptr, csr, Y1, Z1b, inv, N);

    // ---- Layer 2 (MFMA): Y2 bf16, Z2 f32+bias (Z2 overwrites dead pairs region) ----
    gemm2_k<<<(N + 127) / 128, 256, 0, stream>>>(Z1b, W2b, bl2, Y2, Z2, N);

    // ---- out = log_softmax(mean2 + z2) ----
    gather2_logsm_k<<<(N + 15) / 16, 256, 0, stream>>>(row_ptr, csr, Y2, Z2, inv, out, N);
}

// Round 5
// 287.485 us; speedup vs baseline: 14.1847x; 1.0264x over previous
//
#include <hip/hip_runtime.h>
#include <hip/hip_bf16.h>

#define N_NODES 100000
#define IN_C 256
#define HID 128
#define OUT_C 40

#define NPB 9
#define NPP (1 << NPB)                          // 512 nodes per partition
#define NPART ((N_NODES + NPP - 1) >> NPB)      // 196

typedef short bf16x8 __attribute__((ext_vector_type(8)));
typedef float f32x4 __attribute__((ext_vector_type(4)));

static __device__ __forceinline__ float bf2f(unsigned short u) {
    return __uint_as_float(((unsigned)u) << 16);
}
static __device__ __forceinline__ unsigned short f2bf(float f) {
    unsigned u = __float_as_uint(f);
    u += 0x7fffu + ((u >> 16) & 1u);
    return (unsigned short)(u >> 16);
}

// ---------------- A0: partition histogram ----------------
__global__ __launch_bounds__(256) void phist_k(const int* __restrict__ ei, int E, int* __restrict__ pcnt) {
    __shared__ int lh[NPART];
    int tid = threadIdx.x;
    if (tid < NPART) lh[tid] = 0;
    __syncthreads();
    int base = blockIdx.x * 4096;
    int n = min(4096, E - base);
    for (int i = tid; i < n; i += 256)
        atomicAdd(&lh[((unsigned)ei[E + base + i]) >> NPB], 1);
    __syncthreads();
    if (tid < NPART) {
        int c = lh[tid];
        if (c) atomicAdd(&pcnt[tid], c);
    }
}

// ---------------- A1: scan partition counts ----------------
__global__ __launch_bounds__(256) void pscan_k(const int* __restrict__ pcnt, int* __restrict__ pbase,
                                               int* __restrict__ pcur) {
    __shared__ int wsum[4];
    int t = threadIdx.x, lane = t & 63, w = t >> 6;
    int v = (t < NPART) ? pcnt[t] : 0;
    int s = v;
    #pragma unroll
    for (int off = 1; off < 64; off <<= 1) { int x = __shfl_up(s, off); if (lane >= off) s += x; }
    if (lane == 63) wsum[w] = s;
    __syncthreads();
    int woff = 0;
    for (int i = 0; i < w; ++i) woff += wsum[i];
    int excl = woff + s - v;
    if (t < NPART) { pbase[t] = excl; pcur[t] = excl; }
    if (t == 255) pbase[NPART] = woff + s;   // total = E
}

// ---------------- A2: scatter edges into partition-grouped pairs ----------------
__global__ __launch_bounds__(256) void pscatter_k(const int* __restrict__ ei, int E,
                                                  int* __restrict__ pcur, int2* __restrict__ pairs) {
    __shared__ int lh[NPART];
    __shared__ int lb[NPART];
    int tid = threadIdx.x;
    if (tid < NPART) lh[tid] = 0;
    __syncthreads();
    int base = blockIdx.x * 4096;
    int n = min(4096, E - base);
    for (int i = tid; i < n; i += 256)
        atomicAdd(&lh[((unsigned)ei[E + base + i]) >> NPB], 1);
    __syncthreads();
    if (tid < NPART) {
        int c = lh[tid];
        lb[tid] = c ? atomicAdd(&pcur[tid], c) : 0;
        lh[tid] = 0;
    }
    __syncthreads();
    for (int i = tid; i < n; i += 256) {
        int src = ei[base + i];
        int dst = ei[E + base + i];
        int p = ((unsigned)dst) >> NPB;
        int r = atomicAdd(&lh[p], 1);
        pairs[lb[p] + r] = make_int2(src, dst);
    }
}

// ---------------- B: per-partition CSR build (LDS count+scan+fill) ----------------
__global__ __launch_bounds__(256) void pbuild_k(const int2* __restrict__ pairs, const int* __restrict__ pbase,
                                                int* __restrict__ row_ptr, float* __restrict__ inv,
                                                int* __restrict__ csr, int N) {
    __shared__ int cnt[NPP];
    __shared__ int cur[NPP];
    __shared__ int wsum[4];
    int p = blockIdx.x;
    int ebeg = pbase[p], eend = pbase[p + 1];
    int node0 = p << NPB;
    int tid = threadIdx.x;
    cnt[2 * tid] = 0; cnt[2 * tid + 1] = 0;
    __syncthreads();
    for (int e = ebeg + tid; e < eend; e += 256)
        atomicAdd(&cnt[pairs[e].y - node0], 1);
    __syncthreads();
    int c0 = cnt[2 * tid], c1 = cnt[2 * tid + 1];
    int s = c0 + c1;
    int lane = tid & 63, w = tid >> 6;
    int ps = s;
    #pragma unroll
    for (int off = 1; off < 64; off <<= 1) { int x = __shfl_up(ps, off); if (lane >= off) ps += x; }
    if (lane == 63) wsum[w] = ps;
    __syncthreads();
    int woff = 0;
    for (int i = 0; i < w; ++i) woff += wsum[i];
    int excl = woff + ps - s;
    int node = node0 + 2 * tid;
    if (node < N)     { row_ptr[node]     = ebeg + excl;      inv[node]     = 1.f / fmaxf((float)c0, 1.f); }
    if (node + 1 < N) { row_ptr[node + 1] = ebeg + excl + c0; inv[node + 1] = 1.f / fmaxf((float)c1, 1.f); }
    cur[2 * tid] = excl; cur[2 * tid + 1] = excl + c0;
    if (p == NPART - 1 && tid == 255) row_ptr[N] = eend;
    __syncthreads();
    for (int e = ebeg + tid; e < eend; e += 256) {
        int2 pr = pairs[e];
        int r = atomicAdd(&cur[pr.y - node0], 1);
        csr[ebeg + r] = pr.x;
    }
}

// ---------------- f32 -> bf16 convert (n8 = n/8) ----------------
__global__ __launch_bounds__(256) void cvt_k(const float* __restrict__ src, unsigned short* __restrict__ dst, int n8) {
    int i = blockIdx.x * 256 + threadIdx.x;
    if (i >= n8) return;
    float4 v0 = *(const float4*)&src[(size_t)i * 8];
    float4 v1 = *(const float4*)&src[(size_t)i * 8 + 4];
    ushort4 o0, o1;
    o0.x = f2bf(v0.x); o0.y = f2bf(v0.y); o0.z = f2bf(v0.z); o0.w = f2bf(v0.w);
    o1.x = f2bf(v1.x); o1.y = f2bf(v1.y); o1.z = f2bf(v1.z); o1.w = f2bf(v1.w);
    *(ushort4*)&dst[(size_t)i * 8] = o0;
    *(ushort4*)&dst[(size_t)i * 8 + 4] = o1;
}

// ---------------- MFMA GEMM layer1 (fused halves): Y1=bf16(X@Wl^T); Z1b=bf16(X@Wr^T+b) ----------------
// X [M,256] f32, Wb [256,256] bf16 (rows 0-127=Wl, 128-255=Wr)
// 512 threads = 8 waves (2 row-halves x 4 col-quarters); BM=128, BN=256, KCH=64
__global__ __launch_bounds__(512) void gemm1_k(
    const float* __restrict__ X,
    const unsigned short* __restrict__ Wb,
    const float* __restrict__ bias,
    unsigned short* __restrict__ Y,
    unsigned short* __restrict__ Zb,
    int M)
{
    constexpr int LSTR = 72;
    __shared__ unsigned short As[128][LSTR];   // 18.4KB
    __shared__ unsigned short Bs[256][LSTR];   // 36.9KB
    const int tx = threadIdx.x;
    const int rowTile = blockIdx.x * 128;
    const int wv = tx >> 6, ln = tx & 63;
    const int wr = wv >> 2;          // 0..1: 64-row half
    const int wc = wv & 3;           // 0..3: 64-col quarter
    const int lc = ln & 15, lk = (ln >> 4) * 8;
    f32x4 acc[4][4] = {};

    for (int k0 = 0; k0 < 256; k0 += 64) {
        // stage A: 128 rows x 64 k -> 1024 granules of 8, 2 per thread
        #pragma unroll
        for (int i = 0; i < 2; ++i) {
            int idx = i * 512 + tx;
            int r = idx >> 3, kk = (idx & 7) * 8;
            int gr = rowTile + r;
            bf16x8 a = {};
            if (gr < M) {
                const float* p = &X[(size_t)gr * 256 + k0 + kk];
                float4 v0 = *(const float4*)p;
                float4 v1 = *(const float4*)(p + 4);
                a[0] = (short)f2bf(v0.x); a[1] = (short)f2bf(v0.y);
                a[2] = (short)f2bf(v0.z); a[3] = (short)f2bf(v0.w);
                a[4] = (short)f2bf(v1.x); a[5] = (short)f2bf(v1.y);
                a[6] = (short)f2bf(v1.z); a[7] = (short)f2bf(v1.w);
            }
            *(bf16x8*)&As[r][kk] = a;
        }
        // stage B: 256 rows x 64 k -> 2048 granules, 4 per thread
        #pragma unroll
        for (int i = 0; i < 4; ++i) {
            int idx = i * 512 + tx;
            int r = idx >> 3, kk = (idx & 7) * 8;
            *(bf16x8*)&Bs[r][kk] = *(const bf16x8*)&Wb[(size_t)r * 256 + k0 + kk];
        }
        __syncthreads();
        #pragma unroll
        for (int ks = 0; ks < 2; ++ks) {
            int koff = ks * 32 + lk;
            bf16x8 af[4], bfr[4];
            #pragma unroll
            for (int m = 0; m < 4; ++m) af[m] = *(bf16x8*)&As[wr * 64 + m * 16 + lc][koff];
            #pragma unroll
            for (int n = 0; n < 4; ++n) bfr[n] = *(bf16x8*)&Bs[wc * 64 + n * 16 + lc][koff];
            #pragma unroll
            for (int m = 0; m < 4; ++m)
                #pragma unroll
                for (int n = 0; n < 4; ++n)
                    acc[m][n] = __builtin_amdgcn_mfma_f32_16x16x32_bf16(af[m], bfr[n], acc[m][n], 0, 0, 0);
        }
        __syncthreads();
    }

    const int lr4 = (ln >> 4) * 4;
    #pragma unroll
    for (int m = 0; m < 4; ++m) {
        int gr0 = rowTile + wr * 64 + m * 16 + lr4;
        #pragma unroll
        for (int n = 0; n < 4; ++n) {
            int col = wc * 64 + n * 16 + lc;
            float b = (col >= 128) ? bias[col - 128] : 0.f;
            #pragma unroll
            for (int j = 0; j < 4; ++j) {
                int gr = gr0 + j;
                if (gr >= M) continue;
                float v = acc[m][n][j];
                if (col < 128) Y[(size_t)gr * 128 + col] = f2bf(v);
                else           Zb[(size_t)gr * 128 + (col - 128)] = f2bf(v + b);
            }
        }
    }
}

// ---------------- MFMA GEMM layer2 ----------------
__global__ __launch_bounds__(256) void gemm2_k(
    const unsigned short* __restrict__ Hb,
    const unsigned short* __restrict__ Wb,
    const float* __restrict__ bias,
    unsigned short* __restrict__ Y2,
    float* __restrict__ Z2,
    int M)
{
    constexpr int LSTR = 72;
    __shared__ unsigned short As[128][LSTR];
    __shared__ unsigned short Bs[80][LSTR];
    const int tx = threadIdx.x;
    const int rowTile = blockIdx.x * 128;
    const int wv = tx >> 6, ln = tx & 63;
    const int lc = ln & 15, lk = (ln >> 4) * 8;
    f32x4 acc[2][5] = {};

    for (int k0 = 0; k0 < 128; k0 += 64) {
        #pragma unroll
        for (int i = 0; i < 4; ++i) {
            int idx = i * 256 + tx;
            int r = idx >> 3, kk = (idx & 7) * 8;
            int gr = rowTile + r;
            bf16x8 a = {};
            if (gr < M) a = *(const bf16x8*)&Hb[(size_t)gr * 128 + k0 + kk];
            *(bf16x8*)&As[r][kk] = a;
        }
        #pragma unroll
        for (int i = 0; i < 3; ++i) {
            int idx = i * 256 + tx;
            if (idx < 640) {
                int c = idx >> 3, kk = (idx & 7) * 8;
                *(bf16x8*)&Bs[c][kk] = *(const bf16x8*)&Wb[(size_t)c * 128 + k0 + kk];
            }
        }
        __syncthreads();
        #pragma unroll
        for (int ks = 0; ks < 2; ++ks) {
            int koff = ks * 32 + lk;
            bf16x8 af[2], bfr[5];
            #pragma unroll
            for (int m = 0; m < 2; ++m) af[m] = *(bf16x8*)&As[wv * 32 + m * 16 + lc][koff];
            #pragma unroll
            for (int n = 0; n < 5; ++n) bfr[n] = *(bf16x8*)&Bs[n * 16 + lc][koff];
            #pragma unroll
            for (int m = 0; m < 2; ++m)
                #pragma unroll
                for (int n = 0; n < 5; ++n)
                    acc[m][n] = __builtin_amdgcn_mfma_f32_16x16x32_bf16(af[m], bfr[n], acc[m][n], 0, 0, 0);
        }
        __syncthreads();
    }

    const int lr4 = (ln >> 4) * 4;
    #pragma unroll
    for (int m = 0; m < 2; ++m) {
        int gr0 = rowTile + wv * 32 + m * 16 + lr4;
        #pragma unroll
        for (int n = 0; n < 5; ++n) {
            int col = n * 16 + lc;
            #pragma unroll
            for (int j = 0; j < 4; ++j) {
                int gr = gr0 + j;
                if (gr >= M) continue;
                float v = acc[m][n][j];
                if (col < 40) Y2[(size_t)gr * 40 + col] = f2bf(v);
                else          Z2[(size_t)gr * 40 + (col - 40)] = v + bias[col - 40];
            }
        }
    }
}

// ---------------- gather layer 1: h = bf16(relu(mean(Y[src]) + Z)), in place over Zb ----------------
__global__ __launch_bounds__(256) void gather1_k(const int* __restrict__ row_ptr, const int* __restrict__ csr,
                                                 const unsigned short* __restrict__ Y,
                                                 unsigned short* __restrict__ Zb,
                                                 const float* __restrict__ inv, int n) {
    int node = blockIdx.x * 8 + (threadIdx.x >> 5);
    if (node >= n) return;
    int t = threadIdx.x & 31;
    int beg = row_ptr[node], end = row_ptr[node + 1];
    float a0 = 0.f, a1 = 0.f, a2 = 0.f, a3 = 0.f;
    int e = beg;
    for (; e + 4 <= end; e += 4) {
        int s0 = csr[e], s1 = csr[e + 1], s2 = csr[e + 2], s3 = csr[e + 3];
        ushort4 v0 = *(const ushort4*)&Y[(size_t)s0 * HID + t * 4];
        ushort4 v1 = *(const ushort4*)&Y[(size_t)s1 * HID + t * 4];
        ushort4 v2 = *(const ushort4*)&Y[(size_t)s2 * HID + t * 4];
        ushort4 v3 = *(const ushort4*)&Y[(size_t)s3 * HID + t * 4];
        a0 += bf2f(v0.x) + bf2f(v1.x) + bf2f(v2.x) + bf2f(v3.x);
        a1 += bf2f(v0.y) + bf2f(v1.y) + bf2f(v2.y) + bf2f(v3.y);
        a2 += bf2f(v0.z) + bf2f(v1.z) + bf2f(v2.z) + bf2f(v3.z);
        a3 += bf2f(v0.w) + bf2f(v1.w) + bf2f(v2.w) + bf2f(v3.w);
    }
    for (; e < end; ++e) {
        int s0 = csr[e];
        ushort4 v0 = *(const ushort4*)&Y[(size_t)s0 * HID + t * 4];
        a0 += bf2f(v0.x); a1 += bf2f(v0.y); a2 += bf2f(v0.z); a3 += bf2f(v0.w);
    }
    float iv = inv[node];
    ushort4 z = *(const ushort4*)&Zb[(size_t)node * HID + t * 4];
    ushort4 h;
    h.x = f2bf(fmaxf(a0 * iv + bf2f(z.x), 0.f));
    h.y = f2bf(fmaxf(a1 * iv + bf2f(z.y), 0.f));
    h.z = f2bf(fmaxf(a2 * iv + bf2f(z.z), 0.f));
    h.w = f2bf(fmaxf(a3 * iv + bf2f(z.w), 0.f));
    *(ushort4*)&Zb[(size_t)node * HID + t * 4] = h;
}

// ---------------- gather layer 2 + log_softmax ----------------
__global__ __launch_bounds__(256) void gather2_logsm_k(const int* __restrict__ row_ptr, const int* __restrict__ csr,
                                                       const unsigned short* __restrict__ Y, const float* __restrict__ Z,
                                                       const float* __restrict__ inv,
                                                       float* __restrict__ out, int n) {
    int node = blockIdx.x * 16 + (threadIdx.x >> 4);
    if (node >= n) return;
    int t = threadIdx.x & 15;
    float4 v = make_float4(-INFINITY, -INFINITY, -INFINITY, -INFINITY);
    if (t < 10) {
        int beg = row_ptr[node], end = row_ptr[node + 1];
        float4 acc = make_float4(0.f, 0.f, 0.f, 0.f);
        for (int e = beg; e < end; ++e) {
            int s = csr[e];
            ushort4 y = *(const ushort4*)&Y[(size_t)s * OUT_C + t * 4];
            acc.x += bf2f(y.x); acc.y += bf2f(y.y); acc.z += bf2f(y.z); acc.w += bf2f(y.w);
        }
        float iv = inv[node];
        float4 z = *(const float4*)&Z[(size_t)node * OUT_C + t * 4];
        v.x = acc.x * iv + z.x; v.y = acc.y * iv + z.y;
        v.z = acc.z * iv + z.z; v.w = acc.w * iv + z.w;
    }
    float m = fmaxf(fmaxf(v.x, v.y), fmaxf(v.z, v.w));
    #pragma unroll
    for (int off = 8; off; off >>= 1) m = fmaxf(m, __shfl_xor(m, off, 16));
    float s4 = 0.f;
    if (t < 10) s4 = expf(v.x - m) + expf(v.y - m) + expf(v.z - m) + expf(v.w - m);
    #pragma unroll
    for (int off = 8; off; off >>= 1) s4 += __shfl_xor(s4, off, 16);
    float ls = m + logf(s4);
    if (t < 10) {
        float4 o;
        o.x = v.x - ls; o.y = v.y - ls; o.z = v.z - ls; o.w = v.w - ls;
        *(float4*)&out[(size_t)node * OUT_C + t * 4] = o;
    }
}

extern "C" void kernel_launch(void* const* d_in, const int* in_sizes, int n_in,
                              void* d_out, int out_size, void* d_ws, size_t ws_size,
                              hipStream_t stream) {
    const float* x   = (const float*)d_in[0];
    const int*   ei  = (const int*)d_in[1];
    const float* Wl1 = (const float*)d_in[2];
    const float* bl1 = (const float*)d_in[3];
    const float* Wr1 = (const float*)d_in[4];
    const float* Wl2 = (const float*)d_in[5];
    const float* bl2 = (const float*)d_in[6];
    const float* Wr2 = (const float*)d_in[7];
    float* out = (float*)d_out;
    const int N = N_NODES;
    const int E = in_sizes[1] / 2;

    char* ws = (char*)d_ws;
    int*   pcnt    = (int*)(ws + 0x0000);                   // [NPART]
    int*   pbase   = (int*)(ws + 0x1000);                   // [NPART+1]
    int*   pcur    = (int*)(ws + 0x2000);                   // [NPART]
    int*   row_ptr = (int*)(ws + 0x10000);                  // [N+1]
    float* inv     = (float*)(ws + 0x80000);                // [N]
    int*   csr     = (int*)(ws + 0x100000);                 // [E] 6.4MB (1MB..7.4MB)
    int2*  pairs   = (int2*)(ws + 0x800000);                // [E] 12.8MB, dead after pbuild
    float* Z2      = (float*)(ws + 0x800000);               // [N,40] f32 16MB, aliases pairs
    unsigned short* W1b = (unsigned short*)(ws + 0x1900000);// 128KB
    unsigned short* W2b = (unsigned short*)(ws + 0x1930000);// 20KB
    unsigned short* Y1  = (unsigned short*)(ws + 0x1A00000);// [N,128] bf16 25.6MB
    unsigned short* Z1b = (unsigned short*)(ws + 0x3500000);// [N,128] bf16 -> h in place
    unsigned short* Y2  = (unsigned short*)(ws + 0x5200000);// [N,40] bf16 8MB

    // ---- CSR build: partitioned counting sort ----
    hipMemsetAsync(pcnt, 0, NPART * 4, stream);
    int nblk = (E + 4095) / 4096;
    phist_k<<<nblk, 256, 0, stream>>>(ei, E, pcnt);
    pscan_k<<<1, 256, 0, stream>>>(pcnt, pbase, pcur);
    pscatter_k<<<nblk, 256, 0, stream>>>(ei, E, pcur, pairs);
    pbuild_k<<<NPART, 256, 0, stream>>>(pairs, pbase, row_ptr, inv, csr, N);

    // ---- weight conversions ----
    cvt_k<<<16, 256, 0, stream>>>(Wl1, W1b, 4096);
    cvt_k<<<16, 256, 0, stream>>>(Wr1, W1b + 32768, 4096);
    cvt_k<<<3, 256, 0, stream>>>(Wl2, W2b, 640);
    cvt_k<<<3, 256, 0, stream>>>(Wr2, W2b + 5120, 640);

    // ---- Layer 1 (MFMA, fused halves): Y1 + Z1b in one pass ----
    gemm1_k<<<(N + 127) / 128, 512, 0, stream>>>(x, W1b, bl1, Y1, Z1b, N);

    // ---- h = bf16(relu(mean + z)) in place over Z1b ----
    gather1_k<<<N / 8, 256, 0, stream>>>(row_ptr, csr, Y1, Z1b, inv, N);

    // ---- Layer 2 (MFMA): Y2 bf16, Z2 f32+bias ----
    gemm2_k<<<(N + 127) / 128, 256, 0, stream>>>(Z1b, W2b, bl2, Y2, Z2, N);

    // ---- out = log_softmax(mean2 + z2) ----
    gather2_logsm_k<<<(N + 15) / 16, 256, 0, stream>>>(row_ptr, csr, Y2, Z2, inv, out, N);
}

// Round 6
// 271.062 us; speedup vs baseline: 15.0441x; 1.0606x over previous
//
#include <hip/hip_runtime.h>
#include <hip/hip_bf16.h>

#define N_NODES 100000
#define IN_C 256
#define HID 128
#define OUT_C 40

#define NPB 9
#define NPP (1 << NPB)                          // 512 nodes per partition
#define NPART ((N_NODES + NPP - 1) >> NPB)      // 196

typedef short bf16x8 __attribute__((ext_vector_type(8)));
typedef float f32x4 __attribute__((ext_vector_type(4)));

static __device__ __forceinline__ float bf2f(unsigned short u) {
    return __uint_as_float(((unsigned)u) << 16);
}
static __device__ __forceinline__ unsigned short f2bf(float f) {
    unsigned u = __float_as_uint(f);
    u += 0x7fffu + ((u >> 16) & 1u);
    return (unsigned short)(u >> 16);
}

// ---------------- A0: partition histogram ----------------
__global__ __launch_bounds__(256) void phist_k(const int* __restrict__ ei, int E, int* __restrict__ pcnt) {
    __shared__ int lh[NPART];
    int tid = threadIdx.x;
    if (tid < NPART) lh[tid] = 0;
    __syncthreads();
    int base = blockIdx.x * 4096;
    int n = min(4096, E - base);
    for (int i = tid; i < n; i += 256)
        atomicAdd(&lh[((unsigned)ei[E + base + i]) >> NPB], 1);
    __syncthreads();
    if (tid < NPART) {
        int c = lh[tid];
        if (c) atomicAdd(&pcnt[tid], c);
    }
}

// ---------------- A1: scan partition counts ----------------
__global__ __launch_bounds__(256) void pscan_k(const int* __restrict__ pcnt, int* __restrict__ pbase,
                                               int* __restrict__ pcur) {
    __shared__ int wsum[4];
    int t = threadIdx.x, lane = t & 63, w = t >> 6;
    int v = (t < NPART) ? pcnt[t] : 0;
    int s = v;
    #pragma unroll
    for (int off = 1; off < 64; off <<= 1) { int x = __shfl_up(s, off); if (lane >= off) s += x; }
    if (lane == 63) wsum[w] = s;
    __syncthreads();
    int woff = 0;
    for (int i = 0; i < w; ++i) woff += wsum[i];
    int excl = woff + s - v;
    if (t < NPART) { pbase[t] = excl; pcur[t] = excl; }
    if (t == 255) pbase[NPART] = woff + s;   // total = E
}

// ---------------- A2: scatter edges into partition-grouped packed pairs ----------------
// pack = (src << NPB) | (dst & (NPP-1)); src < 2^17, so 26 bits total
__global__ __launch_bounds__(256) void pscatter_k(const int* __restrict__ ei, int E,
                                                  int* __restrict__ pcur, unsigned* __restrict__ pairs) {
    __shared__ int lh[NPART];
    __shared__ int lb[NPART];
    int tid = threadIdx.x;
    if (tid < NPART) lh[tid] = 0;
    __syncthreads();
    int base = blockIdx.x * 4096;
    int n = min(4096, E - base);
    for (int i = tid; i < n; i += 256)
        atomicAdd(&lh[((unsigned)ei[E + base + i]) >> NPB], 1);
    __syncthreads();
    if (tid < NPART) {
        int c = lh[tid];
        lb[tid] = c ? atomicAdd(&pcur[tid], c) : 0;
        lh[tid] = 0;
    }
    __syncthreads();
    for (int i = tid; i < n; i += 256) {
        unsigned src = (unsigned)ei[base + i];
        unsigned dst = (unsigned)ei[E + base + i];
        int p = dst >> NPB;
        int r = atomicAdd(&lh[p], 1);
        pairs[lb[p] + r] = (src << NPB) | (dst & (NPP - 1));
    }
}

// ---------------- B: per-partition CSR build (LDS count+scan+fill) ----------------
__global__ __launch_bounds__(256) void pbuild_k(const unsigned* __restrict__ pairs, const int* __restrict__ pbase,
                                                int* __restrict__ row_ptr, float* __restrict__ inv,
                                                int* __restrict__ csr, int N) {
    __shared__ int cnt[NPP];
    __shared__ int cur[NPP];
    __shared__ int wsum[4];
    int p = blockIdx.x;
    int ebeg = pbase[p], eend = pbase[p + 1];
    int node0 = p << NPB;
    int tid = threadIdx.x;
    cnt[2 * tid] = 0; cnt[2 * tid + 1] = 0;
    __syncthreads();
    for (int e = ebeg + tid; e < eend; e += 256)
        atomicAdd(&cnt[pairs[e] & (NPP - 1)], 1);
    __syncthreads();
    int c0 = cnt[2 * tid], c1 = cnt[2 * tid + 1];
    int s = c0 + c1;
    int lane = tid & 63, w = tid >> 6;
    int ps = s;
    #pragma unroll
    for (int off = 1; off < 64; off <<= 1) { int x = __shfl_up(ps, off); if (lane >= off) ps += x; }
    if (lane == 63) wsum[w] = ps;
    __syncthreads();
    int woff = 0;
    for (int i = 0; i < w; ++i) woff += wsum[i];
    int excl = woff + ps - s;
    int node = node0 + 2 * tid;
    if (node < N)     { row_ptr[node]     = ebeg + excl;      inv[node]     = 1.f / fmaxf((float)c0, 1.f); }
    if (node + 1 < N) { row_ptr[node + 1] = ebeg + excl + c0; inv[node + 1] = 1.f / fmaxf((float)c1, 1.f); }
    cur[2 * tid] = excl; cur[2 * tid + 1] = excl + c0;
    if (p == NPART - 1 && tid == 255) row_ptr[N] = eend;
    __syncthreads();
    for (int e = ebeg + tid; e < eend; e += 256) {
        unsigned pr = pairs[e];
        int r = atomicAdd(&cur[pr & (NPP - 1)], 1);
        csr[ebeg + r] = (int)(pr >> NPB);
    }
}

// ---------------- fused weight convert to fragment-major bf16 ----------------
// W1f: 128 blocks of (c16 0..15, ks 0..7); granule(lane) = W[c16*16+(ln&15)][ks*32+(ln>>4)*8 ..+7]
// W2f: 20 blocks of (c16 0..4, ks 0..3) over K=128
__global__ __launch_bounds__(256) void cvtw_k(
    const float* __restrict__ Wl1, const float* __restrict__ Wr1,
    const float* __restrict__ Wl2, const float* __restrict__ Wr2,
    unsigned short* __restrict__ W1f, unsigned short* __restrict__ W2f)
{
    int gid = blockIdx.x * 256 + threadIdx.x;
    if (gid < 8192) {
        int g = gid;
        int ln = g & 63, blk = g >> 6;
        int c16 = blk >> 3, ks = blk & 7;
        int col = c16 * 16 + (ln & 15);
        int k0 = ks * 32 + (ln >> 4) * 8;
        const float* src = (col < 128) ? &Wl1[(size_t)col * 256 + k0]
                                       : &Wr1[(size_t)(col - 128) * 256 + k0];
        float4 v0 = *(const float4*)src;
        float4 v1 = *(const float4*)(src + 4);
        bf16x8 a;
        a[0] = (short)f2bf(v0.x); a[1] = (short)f2bf(v0.y);
        a[2] = (short)f2bf(v0.z); a[3] = (short)f2bf(v0.w);
        a[4] = (short)f2bf(v1.x); a[5] = (short)f2bf(v1.y);
        a[6] = (short)f2bf(v1.z); a[7] = (short)f2bf(v1.w);
        *(bf16x8*)&W1f[(size_t)g * 8] = a;
    } else if (gid < 9472) {
        int g = gid - 8192;
        int ln = g & 63, blk = g >> 6;
        int c16 = blk >> 2, ks = blk & 3;
        int col = c16 * 16 + (ln & 15);
        int k0 = ks * 32 + (ln >> 4) * 8;
        const float* src = (col < 40) ? &Wl2[(size_t)col * 128 + k0]
                                      : &Wr2[(size_t)(col - 40) * 128 + k0];
        float4 v0 = *(const float4*)src;
        float4 v1 = *(const float4*)(src + 4);
        bf16x8 a;
        a[0] = (short)f2bf(v0.x); a[1] = (short)f2bf(v0.y);
        a[2] = (short)f2bf(v0.z); a[3] = (short)f2bf(v0.w);
        a[4] = (short)f2bf(v1.x); a[5] = (short)f2bf(v1.y);
        a[6] = (short)f2bf(v1.z); a[7] = (short)f2bf(v1.w);
        *(bf16x8*)&W2f[(size_t)g * 8] = a;
    }
}

// ---------------- MFMA GEMM layer1, single-phase K=256 ----------------
// X [M,256] f32; W1f fragment-major; Y1 = bf16(X@Wl^T), Z1b = bf16(X@Wr^T + b)
// 512 threads = 8 waves (2 row-halves x 4 col-quarters); BM=128, BN=256
__global__ __launch_bounds__(512) void gemm1_k(
    const float* __restrict__ X,
    const unsigned short* __restrict__ Wf,
    const float* __restrict__ bias,
    unsigned short* __restrict__ Y,
    unsigned short* __restrict__ Zb,
    int M)
{
    constexpr int KP = 264;                      // 256 + 8 pad (528B row: 2-way bank alias, free)
    __shared__ unsigned short As[128][KP];       // 67.6KB
    const int tx = threadIdx.x;
    const int rowTile = blockIdx.x * 128;
    const int wv = tx >> 6, ln = tx & 63;
    const int wr = wv >> 2;          // 0..1: 64-row half
    const int wc = wv & 3;           // 0..3: 64-col quarter
    const int lc = ln & 15, lk = (ln >> 4) * 8;

    // stage A: 128 rows x 256 k, 4096 granules of 8, 8 per thread (deep burst)
    float4 va[8], vb[8];
    #pragma unroll
    for (int i = 0; i < 8; ++i) {
        int g = i * 512 + tx;
        int r = g >> 5, kk = (g & 31) * 8;
        int gr = rowTile + r;
        if (gr < M) {
            const float* p = &X[(size_t)gr * 256 + kk];
            va[i] = *(const float4*)p;
            vb[i] = *(const float4*)(p + 4);
        } else {
            va[i] = make_float4(0.f, 0.f, 0.f, 0.f);
            vb[i] = make_float4(0.f, 0.f, 0.f, 0.f);
        }
    }
    #pragma unroll
    for (int i = 0; i < 8; ++i) {
        int g = i * 512 + tx;
        int r = g >> 5, kk = (g & 31) * 8;
        bf16x8 a;
        a[0] = (short)f2bf(va[i].x); a[1] = (short)f2bf(va[i].y);
        a[2] = (short)f2bf(va[i].z); a[3] = (short)f2bf(va[i].w);
        a[4] = (short)f2bf(vb[i].x); a[5] = (short)f2bf(vb[i].y);
        a[6] = (short)f2bf(vb[i].z); a[7] = (short)f2bf(vb[i].w);
        *(bf16x8*)&As[r][kk] = a;
    }
    __syncthreads();

    f32x4 acc[4][4] = {};
    #pragma unroll
    for (int ks = 0; ks < 8; ++ks) {
        int koff = ks * 32 + lk;
        bf16x8 bfr[4], af[4];
        #pragma unroll
        for (int n = 0; n < 4; ++n)
            bfr[n] = *(const bf16x8*)&Wf[(size_t)(((wc * 4 + n) * 8 + ks) * 512 + ln * 8)];
        #pragma unroll
        for (int m = 0; m < 4; ++m)
            af[m] = *(const bf16x8*)&As[wr * 64 + m * 16 + lc][koff];
        #pragma unroll
        for (int m = 0; m < 4; ++m)
            #pragma unroll
            for (int n = 0; n < 4; ++n)
                acc[m][n] = __builtin_amdgcn_mfma_f32_16x16x32_bf16(af[m], bfr[n], acc[m][n], 0, 0, 0);
    }

    const int lr4 = (ln >> 4) * 4;
    #pragma unroll
    for (int m = 0; m < 4; ++m) {
        int gr0 = rowTile + wr * 64 + m * 16 + lr4;
        #pragma unroll
        for (int n = 0; n < 4; ++n) {
            int col = wc * 64 + n * 16 + lc;
            float b = (col >= 128) ? bias[col - 128] : 0.f;
            #pragma unroll
            for (int j = 0; j < 4; ++j) {
                int gr = gr0 + j;
                if (gr >= M) continue;
                float v = acc[m][n][j];
                if (col < 128) Y[(size_t)gr * 128 + col] = f2bf(v);
                else           Zb[(size_t)gr * 128 + (col - 128)] = f2bf(v + b);
            }
        }
    }
}

// ---------------- MFMA GEMM layer2, single-phase K=128 ----------------
// Hb [M,128] bf16; W2f fragment-major; cols 0-39 -> Y2 bf16, 40-79 -> Z2 f32+bias
// 256 threads = 4 waves, each 32 rows x 80 cols
__global__ __launch_bounds__(256) void gemm2_k(
    const unsigned short* __restrict__ Hb,
    const unsigned short* __restrict__ Wf,
    const float* __restrict__ bias,
    unsigned short* __restrict__ Y2,
    float* __restrict__ Z2,
    int M)
{
    constexpr int KP = 136;                      // 128 + 8 pad
    __shared__ unsigned short As[128][KP];       // 34.8KB
    const int tx = threadIdx.x;
    const int rowTile = blockIdx.x * 128;
    const int wv = tx >> 6, ln = tx & 63;
    const int lc = ln & 15, lk = (ln >> 4) * 8;

    // stage A: 128 rows x 128 k bf16, 2048 granules, 8 per thread
    #pragma unroll
    for (int i = 0; i < 8; ++i) {
        int g = i * 256 + tx;
        int r = g >> 4, kk = (g & 15) * 8;
        int gr = rowTile + r;
        bf16x8 a = {};
        if (gr < M) a = *(const bf16x8*)&Hb[(size_t)gr * 128 + kk];
        *(bf16x8*)&As[r][kk] = a;
    }
    __syncthreads();

    f32x4 acc[2][5] = {};
    #pragma unroll
    for (int ks = 0; ks < 4; ++ks) {
        int koff = ks * 32 + lk;
        bf16x8 bfr[5], af[2];
        #pragma unroll
        for (int n = 0; n < 5; ++n)
            bfr[n] = *(const bf16x8*)&Wf[(size_t)((n * 4 + ks) * 512 + ln * 8)];
        #pragma unroll
        for (int m = 0; m < 2; ++m)
            af[m] = *(const bf16x8*)&As[wv * 32 + m * 16 + lc][koff];
        #pragma unroll
        for (int m = 0; m < 2; ++m)
            #pragma unroll
            for (int n = 0; n < 5; ++n)
                acc[m][n] = __builtin_amdgcn_mfma_f32_16x16x32_bf16(af[m], bfr[n], acc[m][n], 0, 0, 0);
    }

    const int lr4 = (ln >> 4) * 4;
    #pragma unroll
    for (int m = 0; m < 2; ++m) {
        int gr0 = rowTile + wv * 32 + m * 16 + lr4;
        #pragma unroll
        for (int n = 0; n < 5; ++n) {
            int col = n * 16 + lc;
            #pragma unroll
            for (int j = 0; j < 4; ++j) {
                int gr = gr0 + j;
                if (gr >= M) continue;
                float v = acc[m][n][j];
                if (col < 40) Y2[(size_t)gr * 40 + col] = f2bf(v);
                else          Z2[(size_t)gr * 40 + (col - 40)] = v + bias[col - 40];
            }
        }
    }
}

// ---------------- gather layer 1: h = bf16(relu(mean(Y[src]) + Z)), in place over Zb ----------------
__global__ __launch_bounds__(256) void gather1_k(const int* __restrict__ row_ptr, const int* __restrict__ csr,
                                                 const unsigned short* __restrict__ Y,
                                                 unsigned short* __restrict__ Zb,
                                                 const float* __restrict__ inv, int n) {
    int node = blockIdx.x * 8 + (threadIdx.x >> 5);
    if (node >= n) return;
    int t = threadIdx.x & 31;
    int beg = row_ptr[node], end = row_ptr[node + 1];
    float a0 = 0.f, a1 = 0.f, a2 = 0.f, a3 = 0.f;
    int e = beg;
    for (; e + 4 <= end; e += 4) {
        int s0 = csr[e], s1 = csr[e + 1], s2 = csr[e + 2], s3 = csr[e + 3];
        ushort4 v0 = *(const ushort4*)&Y[(size_t)s0 * HID + t * 4];
        ushort4 v1 = *(const ushort4*)&Y[(size_t)s1 * HID + t * 4];
        ushort4 v2 = *(const ushort4*)&Y[(size_t)s2 * HID + t * 4];
        ushort4 v3 = *(const ushort4*)&Y[(size_t)s3 * HID + t * 4];
        a0 += bf2f(v0.x) + bf2f(v1.x) + bf2f(v2.x) + bf2f(v3.x);
        a1 += bf2f(v0.y) + bf2f(v1.y) + bf2f(v2.y) + bf2f(v3.y);
        a2 += bf2f(v0.z) + bf2f(v1.z) + bf2f(v2.z) + bf2f(v3.z);
        a3 += bf2f(v0.w) + bf2f(v1.w) + bf2f(v2.w) + bf2f(v3.w);
    }
    for (; e < end; ++e) {
        int s0 = csr[e];
        ushort4 v0 = *(const ushort4*)&Y[(size_t)s0 * HID + t * 4];
        a0 += bf2f(v0.x); a1 += bf2f(v0.y); a2 += bf2f(v0.z); a3 += bf2f(v0.w);
    }
    float iv = inv[node];
    ushort4 z = *(const ushort4*)&Zb[(size_t)node * HID + t * 4];
    ushort4 h;
    h.x = f2bf(fmaxf(a0 * iv + bf2f(z.x), 0.f));
    h.y = f2bf(fmaxf(a1 * iv + bf2f(z.y), 0.f));
    h.z = f2bf(fmaxf(a2 * iv + bf2f(z.z), 0.f));
    h.w = f2bf(fmaxf(a3 * iv + bf2f(z.w), 0.f));
    *(ushort4*)&Zb[(size_t)node * HID + t * 4] = h;
}

// ---------------- gather layer 2 + log_softmax ----------------
__global__ __launch_bounds__(256) void gather2_logsm_k(const int* __restrict__ row_ptr, const int* __restrict__ csr,
                                                       const unsigned short* __restrict__ Y, const float* __restrict__ Z,
                                                       const float* __restrict__ inv,
                                                       float* __restrict__ out, int n) {
    int node = blockIdx.x * 16 + (threadIdx.x >> 4);
    if (node >= n) return;
    int t = threadIdx.x & 15;
    float4 v = make_float4(-INFINITY, -INFINITY, -INFINITY, -INFINITY);
    if (t < 10) {
        int beg = row_ptr[node], end = row_ptr[node + 1];
        float4 acc = make_float4(0.f, 0.f, 0.f, 0.f);
        for (int e = beg; e < end; ++e) {
            int s = csr[e];
            ushort4 y = *(const ushort4*)&Y[(size_t)s * OUT_C + t * 4];
            acc.x += bf2f(y.x); acc.y += bf2f(y.y); acc.z += bf2f(y.z); acc.w += bf2f(y.w);
        }
        float iv = inv[node];
        float4 z = *(const float4*)&Z[(size_t)node * OUT_C + t * 4];
        v.x = acc.x * iv + z.x; v.y = acc.y * iv + z.y;
        v.z = acc.z * iv + z.z; v.w = acc.w * iv + z.w;
    }
    float m = fmaxf(fmaxf(v.x, v.y), fmaxf(v.z, v.w));
    #pragma unroll
    for (int off = 8; off; off >>= 1) m = fmaxf(m, __shfl_xor(m, off, 16));
    float s4 = 0.f;
    if (t < 10) s4 = expf(v.x - m) + expf(v.y - m) + expf(v.z - m) + expf(v.w - m);
    #pragma unroll
    for (int off = 8; off; off >>= 1) s4 += __shfl_xor(s4, off, 16);
    float ls = m + logf(s4);
    if (t < 10) {
        float4 o;
        o.x = v.x - ls; o.y = v.y - ls; o.z = v.z - ls; o.w = v.w - ls;
        *(float4*)&out[(size_t)node * OUT_C + t * 4] = o;
    }
}

extern "C" void kernel_launch(void* const* d_in, const int* in_sizes, int n_in,
                              void* d_out, int out_size, void* d_ws, size_t ws_size,
                              hipStream_t stream) {
    const float* x   = (const float*)d_in[0];
    const int*   ei  = (const int*)d_in[1];
    const float* Wl1 = (const float*)d_in[2];
    const float* bl1 = (const float*)d_in[3];
    const float* Wr1 = (const float*)d_in[4];
    const float* Wl2 = (const float*)d_in[5];
    const float* bl2 = (const float*)d_in[6];
    const float* Wr2 = (const float*)d_in[7];
    float* out = (float*)d_out;
    const int N = N_NODES;
    const int E = in_sizes[1] / 2;

    char* ws = (char*)d_ws;
    int*   pcnt    = (int*)(ws + 0x0000);                   // [NPART]
    int*   pbase   = (int*)(ws + 0x1000);                   // [NPART+1]
    int*   pcur    = (int*)(ws + 0x2000);                   // [NPART]
    int*   row_ptr = (int*)(ws + 0x10000);                  // [N+1]
    float* inv     = (float*)(ws + 0x80000);                // [N]
    int*   csr     = (int*)(ws + 0x100000);                 // [E] 6.4MB (1MB..7.4MB)
    unsigned* pairs = (unsigned*)(ws + 0x800000);           // [E] 6.4MB packed, dead after pbuild
    float* Z2      = (float*)(ws + 0x800000);               // [N,40] f32 16MB, aliases pairs
    unsigned short* W1f = (unsigned short*)(ws + 0x1900000);// 128KB fragment-major
    unsigned short* W2f = (unsigned short*)(ws + 0x1930000);// 20KB fragment-major
    unsigned short* Y1  = (unsigned short*)(ws + 0x1A00000);// [N,128] bf16 25.6MB
    unsigned short* Z1b = (unsigned short*)(ws + 0x3500000);// [N,128] bf16 -> h in place
    unsigned short* Y2  = (unsigned short*)(ws + 0x5200000);// [N,40] bf16 8MB

    // ---- CSR build: partitioned counting sort (packed 32-bit pairs) ----
    hipMemsetAsync(pcnt, 0, NPART * 4, stream);
    int nblk = (E + 4095) / 4096;
    phist_k<<<nblk, 256, 0, stream>>>(ei, E, pcnt);
    pscan_k<<<1, 256, 0, stream>>>(pcnt, pbase, pcur);
    pscatter_k<<<nblk, 256, 0, stream>>>(ei, E, pcur, pairs);
    pbuild_k<<<NPART, 256, 0, stream>>>(pairs, pbase, row_ptr, inv, csr, N);

    // ---- fused weight conversion to fragment-major ----
    cvtw_k<<<37, 256, 0, stream>>>(Wl1, Wr1, Wl2, Wr2, W1f, W2f);

    // ---- Layer 1 (MFMA, single-phase): Y1 + Z1b ----
    gemm1_k<<<(N + 127) / 128, 512, 0, stream>>>(x, W1f, bl1, Y1, Z1b, N);

    // ---- h = bf16(relu(mean + z)) in place over Z1b ----
    gather1_k<<<N / 8, 256, 0, stream>>>(row_ptr, csr, Y1, Z1b, inv, N);

    // ---- Layer 2 (MFMA, single-phase): Y2 bf16, Z2 f32+bias ----
    gemm2_k<<<(N + 127) / 128, 256, 0, stream>>>(Z1b, W2f, bl2, Y2, Z2, N);

    // ---- out = log_softmax(mean2 + z2) ----
    gather2_logsm_k<<<(N + 15) / 16, 256, 0, stream>>>(row_ptr, csr, Y2, Z2, inv, out, N);
}

// Round 7
// 247.227 us; speedup vs baseline: 16.4946x; 1.0964x over previous
//
#include <hip/hip_runtime.h>
#include <hip/hip_bf16.h>

#define N_NODES 100000
#define IN_C 256
#define HID 128
#define OUT_C 40

#define NPB 9
#define NPP (1 << NPB)                          // 512 nodes per partition
#define NPART ((N_NODES + NPP - 1) >> NPB)      // 196

typedef short bf16x8 __attribute__((ext_vector_type(8)));
typedef float f32x4 __attribute__((ext_vector_type(4)));

static __device__ __forceinline__ float bf2f(unsigned short u) {
    return __uint_as_float(((unsigned)u) << 16);
}
static __device__ __forceinline__ unsigned short f2bf(float f) {
    unsigned u = __float_as_uint(f);
    u += 0x7fffu + ((u >> 16) & 1u);
    return (unsigned short)(u >> 16);
}

// ---------------- A0: partition histogram ----------------
__global__ __launch_bounds__(256) void phist_k(const int* __restrict__ ei, int E, int* __restrict__ pcnt) {
    __shared__ int lh[NPART];
    int tid = threadIdx.x;
    if (tid < NPART) lh[tid] = 0;
    __syncthreads();
    int base = blockIdx.x * 4096;
    int n = min(4096, E - base);
    for (int i = tid; i < n; i += 256)
        atomicAdd(&lh[((unsigned)ei[E + base + i]) >> NPB], 1);
    __syncthreads();
    if (tid < NPART) {
        int c = lh[tid];
        if (c) atomicAdd(&pcnt[tid], c);
    }
}

// ---------------- A1: scan partition counts ----------------
__global__ __launch_bounds__(256) void pscan_k(const int* __restrict__ pcnt, int* __restrict__ pbase,
                                               int* __restrict__ pcur) {
    __shared__ int wsum[4];
    int t = threadIdx.x, lane = t & 63, w = t >> 6;
    int v = (t < NPART) ? pcnt[t] : 0;
    int s = v;
    #pragma unroll
    for (int off = 1; off < 64; off <<= 1) { int x = __shfl_up(s, off); if (lane >= off) s += x; }
    if (lane == 63) wsum[w] = s;
    __syncthreads();
    int woff = 0;
    for (int i = 0; i < w; ++i) woff += wsum[i];
    int excl = woff + s - v;
    if (t < NPART) { pbase[t] = excl; pcur[t] = excl; }
    if (t == 255) pbase[NPART] = woff + s;   // total = E
}

// ---------------- A2: scatter edges into partition-grouped packed pairs ----------------
__global__ __launch_bounds__(256) void pscatter_k(const int* __restrict__ ei, int E,
                                                  int* __restrict__ pcur, unsigned* __restrict__ pairs) {
    __shared__ int lh[NPART];
    __shared__ int lb[NPART];
    int tid = threadIdx.x;
    if (tid < NPART) lh[tid] = 0;
    __syncthreads();
    int base = blockIdx.x * 4096;
    int n = min(4096, E - base);
    for (int i = tid; i < n; i += 256)
        atomicAdd(&lh[((unsigned)ei[E + base + i]) >> NPB], 1);
    __syncthreads();
    if (tid < NPART) {
        int c = lh[tid];
        lb[tid] = c ? atomicAdd(&pcur[tid], c) : 0;
        lh[tid] = 0;
    }
    __syncthreads();
    for (int i = tid; i < n; i += 256) {
        unsigned src = (unsigned)ei[base + i];
        unsigned dst = (unsigned)ei[E + base + i];
        int p = dst >> NPB;
        int r = atomicAdd(&lh[p], 1);
        pairs[lb[p] + r] = (src << NPB) | (dst & (NPP - 1));
    }
}

// ---------------- B: per-partition CSR build (LDS count+scan+fill) ----------------
__global__ __launch_bounds__(256) void pbuild_k(const unsigned* __restrict__ pairs, const int* __restrict__ pbase,
                                                int* __restrict__ row_ptr, float* __restrict__ inv,
                                                int* __restrict__ csr, int N) {
    __shared__ int cnt[NPP];
    __shared__ int cur[NPP];
    __shared__ int wsum[4];
    int p = blockIdx.x;
    int ebeg = pbase[p], eend = pbase[p + 1];
    int node0 = p << NPB;
    int tid = threadIdx.x;
    cnt[2 * tid] = 0; cnt[2 * tid + 1] = 0;
    __syncthreads();
    for (int e = ebeg + tid; e < eend; e += 256)
        atomicAdd(&cnt[pairs[e] & (NPP - 1)], 1);
    __syncthreads();
    int c0 = cnt[2 * tid], c1 = cnt[2 * tid + 1];
    int s = c0 + c1;
    int lane = tid & 63, w = tid >> 6;
    int ps = s;
    #pragma unroll
    for (int off = 1; off < 64; off <<= 1) { int x = __shfl_up(ps, off); if (lane >= off) ps += x; }
    if (lane == 63) wsum[w] = ps;
    __syncthreads();
    int woff = 0;
    for (int i = 0; i < w; ++i) woff += wsum[i];
    int excl = woff + ps - s;
    int node = node0 + 2 * tid;
    if (node < N)     { row_ptr[node]     = ebeg + excl;      inv[node]     = 1.f / fmaxf((float)c0, 1.f); }
    if (node + 1 < N) { row_ptr[node + 1] = ebeg + excl + c0; inv[node + 1] = 1.f / fmaxf((float)c1, 1.f); }
    cur[2 * tid] = excl; cur[2 * tid + 1] = excl + c0;
    if (p == NPART - 1 && tid == 255) row_ptr[N] = eend;
    __syncthreads();
    for (int e = ebeg + tid; e < eend; e += 256) {
        unsigned pr = pairs[e];
        int r = atomicAdd(&cur[pr & (NPP - 1)], 1);
        csr[ebeg + r] = (int)(pr >> NPB);
    }
}

// ---------------- fused weight convert to fragment-major bf16 ----------------
__global__ __launch_bounds__(256) void cvtw_k(
    const float* __restrict__ Wl1, const float* __restrict__ Wr1,
    const float* __restrict__ Wl2, const float* __restrict__ Wr2,
    unsigned short* __restrict__ W1f, unsigned short* __restrict__ W2f)
{
    int gid = blockIdx.x * 256 + threadIdx.x;
    if (gid < 8192) {
        int g = gid;
        int ln = g & 63, blk = g >> 6;
        int c16 = blk >> 3, ks = blk & 7;
        int col = c16 * 16 + (ln & 15);
        int k0 = ks * 32 + (ln >> 4) * 8;
        const float* src = (col < 128) ? &Wl1[(size_t)col * 256 + k0]
                                       : &Wr1[(size_t)(col - 128) * 256 + k0];
        float4 v0 = *(const float4*)src;
        float4 v1 = *(const float4*)(src + 4);
        bf16x8 a;
        a[0] = (short)f2bf(v0.x); a[1] = (short)f2bf(v0.y);
        a[2] = (short)f2bf(v0.z); a[3] = (short)f2bf(v0.w);
        a[4] = (short)f2bf(v1.x); a[5] = (short)f2bf(v1.y);
        a[6] = (short)f2bf(v1.z); a[7] = (short)f2bf(v1.w);
        *(bf16x8*)&W1f[(size_t)g * 8] = a;
    } else if (gid < 9472) {
        int g = gid - 8192;
        int ln = g & 63, blk = g >> 6;
        int c16 = blk >> 2, ks = blk & 3;
        int col = c16 * 16 + (ln & 15);
        int k0 = ks * 32 + (ln >> 4) * 8;
        const float* src = (col < 40) ? &Wl2[(size_t)col * 128 + k0]
                                      : &Wr2[(size_t)(col - 40) * 128 + k0];
        float4 v0 = *(const float4*)src;
        float4 v1 = *(const float4*)(src + 4);
        bf16x8 a;
        a[0] = (short)f2bf(v0.x); a[1] = (short)f2bf(v0.y);
        a[2] = (short)f2bf(v0.z); a[3] = (short)f2bf(v0.w);
        a[4] = (short)f2bf(v1.x); a[5] = (short)f2bf(v1.y);
        a[6] = (short)f2bf(v1.z); a[7] = (short)f2bf(v1.w);
        *(bf16x8*)&W2f[(size_t)g * 8] = a;
    }
}

// ---------------- MFMA GEMM layer1, single-phase K=256, LDS-transposed epilogue ----------------
// X [M,256] f32; W1f fragment-major; Y1 = bf16(X@Wl^T), Z1b = bf16(X@Wr^T + b)
__global__ __launch_bounds__(512) void gemm1_k(
    const float* __restrict__ X,
    const unsigned short* __restrict__ Wf,
    const float* __restrict__ bias,
    unsigned short* __restrict__ Y,
    unsigned short* __restrict__ Zb,
    int M)
{
    constexpr int KP = 264;                      // 256 + 8 pad
    __shared__ unsigned short As[128][KP];       // 67.6KB; reused as output tile [128][256]
    const int tx = threadIdx.x;
    const int rowTile = blockIdx.x * 128;
    const int wv = tx >> 6, ln = tx & 63;
    const int wr = wv >> 2;          // 0..1: 64-row half
    const int wc = wv & 3;           // 0..3: 64-col quarter
    const int lc = ln & 15, lk = (ln >> 4) * 8;

    // stage A: 128 rows x 256 k, 8 granules per thread (deep burst)
    float4 va[8], vb[8];
    #pragma unroll
    for (int i = 0; i < 8; ++i) {
        int g = i * 512 + tx;
        int r = g >> 5, kk = (g & 31) * 8;
        int gr = rowTile + r;
        if (gr < M) {
            const float* p = &X[(size_t)gr * 256 + kk];
            va[i] = *(const float4*)p;
            vb[i] = *(const float4*)(p + 4);
        } else {
            va[i] = make_float4(0.f, 0.f, 0.f, 0.f);
            vb[i] = make_float4(0.f, 0.f, 0.f, 0.f);
        }
    }
    #pragma unroll
    for (int i = 0; i < 8; ++i) {
        int g = i * 512 + tx;
        int r = g >> 5, kk = (g & 31) * 8;
        bf16x8 a;
        a[0] = (short)f2bf(va[i].x); a[1] = (short)f2bf(va[i].y);
        a[2] = (short)f2bf(va[i].z); a[3] = (short)f2bf(va[i].w);
        a[4] = (short)f2bf(vb[i].x); a[5] = (short)f2bf(vb[i].y);
        a[6] = (short)f2bf(vb[i].z); a[7] = (short)f2bf(vb[i].w);
        *(bf16x8*)&As[r][kk] = a;
    }
    __syncthreads();

    f32x4 acc[4][4] = {};
    #pragma unroll
    for (int ks = 0; ks < 8; ++ks) {
        int koff = ks * 32 + lk;
        bf16x8 bfr[4], af[4];
        #pragma unroll
        for (int n = 0; n < 4; ++n)
            bfr[n] = *(const bf16x8*)&Wf[(size_t)(((wc * 4 + n) * 8 + ks) * 512 + ln * 8)];
        #pragma unroll
        for (int m = 0; m < 4; ++m)
            af[m] = *(const bf16x8*)&As[wr * 64 + m * 16 + lc][koff];
        #pragma unroll
        for (int m = 0; m < 4; ++m)
            #pragma unroll
            for (int n = 0; n < 4; ++n)
                acc[m][n] = __builtin_amdgcn_mfma_f32_16x16x32_bf16(af[m], bfr[n], acc[m][n], 0, 0, 0);
    }

    // epilogue: acc -> LDS (transpose to row-major bf16), then packed 16B global stores
    __syncthreads();   // all waves done reading As
    const int lr4 = (ln >> 4) * 4;
    #pragma unroll
    for (int m = 0; m < 4; ++m) {
        int r0 = wr * 64 + m * 16 + lr4;
        #pragma unroll
        for (int n = 0; n < 4; ++n) {
            int col = wc * 64 + n * 16 + lc;
            float b = (col >= 128) ? bias[col - 128] : 0.f;
            #pragma unroll
            for (int j = 0; j < 4; ++j)
                As[r0 + j][col] = f2bf(acc[m][n][j] + b);
        }
    }
    __syncthreads();
    #pragma unroll
    for (int i = 0; i < 8; ++i) {
        int g = i * 512 + tx;
        int r = g >> 5, c8 = (g & 31) * 8;
        int gr = rowTile + r;
        if (gr >= M) continue;
        bf16x8 v = *(const bf16x8*)&As[r][c8];
        if (c8 < 128) *(bf16x8*)&Y[(size_t)gr * 128 + c8] = v;
        else          *(bf16x8*)&Zb[(size_t)gr * 128 + (c8 - 128)] = v;
    }
}

// ---------------- MFMA GEMM layer2, single-phase K=128, LDS-transposed epilogue ----------------
// Hb [M,128] bf16; W2f fragment-major; cols 0-39 -> Y2 bf16, 40-79 -> Z2b bf16(+bias)
__global__ __launch_bounds__(256) void gemm2_k(
    const unsigned short* __restrict__ Hb,
    const unsigned short* __restrict__ Wf,
    const float* __restrict__ bias,
    unsigned short* __restrict__ Y2,
    unsigned short* __restrict__ Z2b,
    int M)
{
    constexpr int KP = 136;                      // 128 + 8 pad
    __shared__ unsigned short As[128][KP];       // 34.8KB; reused as output tile [128][96]
    const int tx = threadIdx.x;
    const int rowTile = blockIdx.x * 128;
    const int wv = tx >> 6, ln = tx & 63;
    const int lc = ln & 15, lk = (ln >> 4) * 8;

    #pragma unroll
    for (int i = 0; i < 8; ++i) {
        int g = i * 256 + tx;
        int r = g >> 4, kk = (g & 15) * 8;
        int gr = rowTile + r;
        bf16x8 a = {};
        if (gr < M) a = *(const bf16x8*)&Hb[(size_t)gr * 128 + kk];
        *(bf16x8*)&As[r][kk] = a;
    }
    __syncthreads();

    f32x4 acc[2][5] = {};
    #pragma unroll
    for (int ks = 0; ks < 4; ++ks) {
        int koff = ks * 32 + lk;
        bf16x8 bfr[5], af[2];
        #pragma unroll
        for (int n = 0; n < 5; ++n)
            bfr[n] = *(const bf16x8*)&Wf[(size_t)((n * 4 + ks) * 512 + ln * 8)];
        #pragma unroll
        for (int m = 0; m < 2; ++m)
            af[m] = *(const bf16x8*)&As[wv * 32 + m * 16 + lc][koff];
        #pragma unroll
        for (int m = 0; m < 2; ++m)
            #pragma unroll
            for (int n = 0; n < 5; ++n)
                acc[m][n] = __builtin_amdgcn_mfma_f32_16x16x32_bf16(af[m], bfr[n], acc[m][n], 0, 0, 0);
    }

    __syncthreads();
    unsigned short (*OutL)[96] = (unsigned short (*)[96])&As[0][0];  // [128][96] bf16 = 24.6KB
    const int lr4 = (ln >> 4) * 4;
    #pragma unroll
    for (int m = 0; m < 2; ++m) {
        int r0 = wv * 32 + m * 16 + lr4;
        #pragma unroll
        for (int n = 0; n < 5; ++n) {
            int col = n * 16 + lc;
            float b = (col >= 40) ? bias[col - 40] : 0.f;
            #pragma unroll
            for (int j = 0; j < 4; ++j)
                OutL[r0 + j][col] = f2bf(acc[m][n][j] + b);
        }
    }
    __syncthreads();
    #pragma unroll
    for (int i = 0; i < 5; ++i) {
        int g = i * 256 + tx;            // 1280 granules = 128 rows x 10
        int r = g / 10, cg = g % 10;
        int c8 = cg * 8;
        int gr = rowTile + r;
        if (gr >= M) continue;
        bf16x8 v = *(const bf16x8*)&OutL[r][c8];
        if (c8 < 40) *(bf16x8*)&Y2[(size_t)gr * 40 + c8] = v;
        else         *(bf16x8*)&Z2b[(size_t)gr * 40 + (c8 - 40)] = v;
    }
}

// ---------------- gather layer 1: h = bf16(relu(mean(Y[src]) + Z)), in place over Zb ----------------
__global__ __launch_bounds__(256) void gather1_k(const int* __restrict__ row_ptr, const int* __restrict__ csr,
                                                 const unsigned short* __restrict__ Y,
                                                 unsigned short* __restrict__ Zb,
                                                 const float* __restrict__ inv, int n) {
    int node = blockIdx.x * 8 + (threadIdx.x >> 5);
    if (node >= n) return;
    int t = threadIdx.x & 31;
    int beg = row_ptr[node], end = row_ptr[node + 1];
    float a0 = 0.f, a1 = 0.f, a2 = 0.f, a3 = 0.f;
    int e = beg;
    for (; e + 4 <= end; e += 4) {
        int s0 = csr[e], s1 = csr[e + 1], s2 = csr[e + 2], s3 = csr[e + 3];
        ushort4 v0 = *(const ushort4*)&Y[(size_t)s0 * HID + t * 4];
        ushort4 v1 = *(const ushort4*)&Y[(size_t)s1 * HID + t * 4];
        ushort4 v2 = *(const ushort4*)&Y[(size_t)s2 * HID + t * 4];
        ushort4 v3 = *(const ushort4*)&Y[(size_t)s3 * HID + t * 4];
        a0 += bf2f(v0.x) + bf2f(v1.x) + bf2f(v2.x) + bf2f(v3.x);
        a1 += bf2f(v0.y) + bf2f(v1.y) + bf2f(v2.y) + bf2f(v3.y);
        a2 += bf2f(v0.z) + bf2f(v1.z) + bf2f(v2.z) + bf2f(v3.z);
        a3 += bf2f(v0.w) + bf2f(v1.w) + bf2f(v2.w) + bf2f(v3.w);
    }
    for (; e < end; ++e) {
        int s0 = csr[e];
        ushort4 v0 = *(const ushort4*)&Y[(size_t)s0 * HID + t * 4];
        a0 += bf2f(v0.x); a1 += bf2f(v0.y); a2 += bf2f(v0.z); a3 += bf2f(v0.w);
    }
    float iv = inv[node];
    ushort4 z = *(const ushort4*)&Zb[(size_t)node * HID + t * 4];
    ushort4 h;
    h.x = f2bf(fmaxf(a0 * iv + bf2f(z.x), 0.f));
    h.y = f2bf(fmaxf(a1 * iv + bf2f(z.y), 0.f));
    h.z = f2bf(fmaxf(a2 * iv + bf2f(z.z), 0.f));
    h.w = f2bf(fmaxf(a3 * iv + bf2f(z.w), 0.f));
    *(ushort4*)&Zb[(size_t)node * HID + t * 4] = h;
}

// ---------------- gather layer 2 + log_softmax ----------------
__global__ __launch_bounds__(256) void gather2_logsm_k(const int* __restrict__ row_ptr, const int* __restrict__ csr,
                                                       const unsigned short* __restrict__ Y,
                                                       const unsigned short* __restrict__ Zb,
                                                       const float* __restrict__ inv,
                                                       float* __restrict__ out, int n) {
    int node = blockIdx.x * 16 + (threadIdx.x >> 4);
    if (node >= n) return;
    int t = threadIdx.x & 15;
    float4 v = make_float4(-INFINITY, -INFINITY, -INFINITY, -INFINITY);
    if (t < 10) {
        int beg = row_ptr[node], end = row_ptr[node + 1];
        float4 acc = make_float4(0.f, 0.f, 0.f, 0.f);
        for (int e = beg; e < end; ++e) {
            int s = csr[e];
            ushort4 y = *(const ushort4*)&Y[(size_t)s * OUT_C + t * 4];
            acc.x += bf2f(y.x); acc.y += bf2f(y.y); acc.z += bf2f(y.z); acc.w += bf2f(y.w);
        }
        float iv = inv[node];
        ushort4 z = *(const ushort4*)&Zb[(size_t)node * OUT_C + t * 4];
        v.x = acc.x * iv + bf2f(z.x); v.y = acc.y * iv + bf2f(z.y);
        v.z = acc.z * iv + bf2f(z.z); v.w = acc.w * iv + bf2f(z.w);
    }
    float m = fmaxf(fmaxf(v.x, v.y), fmaxf(v.z, v.w));
    #pragma unroll
    for (int off = 8; off; off >>= 1) m = fmaxf(m, __shfl_xor(m, off, 16));
    float s4 = 0.f;
    if (t < 10) s4 = expf(v.x - m) + expf(v.y - m) + expf(v.z - m) + expf(v.w - m);
    #pragma unroll
    for (int off = 8; off; off >>= 1) s4 += __shfl_xor(s4, off, 16);
    float ls = m + logf(s4);
    if (t < 10) {
        float4 o;
        o.x = v.x - ls; o.y = v.y - ls; o.z = v.z - ls; o.w = v.w - ls;
        *(float4*)&out[(size_t)node * OUT_C + t * 4] = o;
    }
}

extern "C" void kernel_launch(void* const* d_in, const int* in_sizes, int n_in,
                              void* d_out, int out_size, void* d_ws, size_t ws_size,
                              hipStream_t stream) {
    const float* x   = (const float*)d_in[0];
    const int*   ei  = (const int*)d_in[1];
    const float* Wl1 = (const float*)d_in[2];
    const float* bl1 = (const float*)d_in[3];
    const float* Wr1 = (const float*)d_in[4];
    const float* Wl2 = (const float*)d_in[5];
    const float* bl2 = (const float*)d_in[6];
    const float* Wr2 = (const float*)d_in[7];
    float* out = (float*)d_out;
    const int N = N_NODES;
    const int E = in_sizes[1] / 2;

    char* ws = (char*)d_ws;
    int*   pcnt    = (int*)(ws + 0x0000);                   // [NPART]
    int*   pbase   = (int*)(ws + 0x1000);                   // [NPART+1]
    int*   pcur    = (int*)(ws + 0x2000);                   // [NPART]
    int*   row_ptr = (int*)(ws + 0x10000);                  // [N+1]
    float* inv     = (float*)(ws + 0x80000);                // [N]
    int*   csr     = (int*)(ws + 0x100000);                 // [E] 6.4MB (1MB..7.4MB)
    unsigned* pairs = (unsigned*)(ws + 0x800000);           // [E] 6.4MB packed, dead after pbuild
    unsigned short* Z2b = (unsigned short*)(ws + 0x800000); // [N,40] bf16 8MB, aliases pairs
    unsigned short* W1f = (unsigned short*)(ws + 0x1900000);// 128KB fragment-major
    unsigned short* W2f = (unsigned short*)(ws + 0x1930000);// 20KB fragment-major
    unsigned short* Y1  = (unsigned short*)(ws + 0x1A00000);// [N,128] bf16 25.6MB
    unsigned short* Z1b = (unsigned short*)(ws + 0x3500000);// [N,128] bf16 -> h in place
    unsigned short* Y2  = (unsigned short*)(ws + 0x5200000);// [N,40] bf16 8MB

    // ---- CSR build: partitioned counting sort (packed 32-bit pairs) ----
    hipMemsetAsync(pcnt, 0, NPART * 4, stream);
    int nblk = (E + 4095) / 4096;
    phist_k<<<nblk, 256, 0, stream>>>(ei, E, pcnt);
    pscan_k<<<1, 256, 0, stream>>>(pcnt, pbase, pcur);
    pscatter_k<<<nblk, 256, 0, stream>>>(ei, E, pcur, pairs);
    pbuild_k<<<NPART, 256, 0, stream>>>(pairs, pbase, row_ptr, inv, csr, N);

    // ---- fused weight conversion to fragment-major ----
    cvtw_k<<<37, 256, 0, stream>>>(Wl1, Wr1, Wl2, Wr2, W1f, W2f);

    // ---- Layer 1 (MFMA, single-phase): Y1 + Z1b ----
    gemm1_k<<<(N + 127) / 128, 512, 0, stream>>>(x, W1f, bl1, Y1, Z1b, N);

    // ---- h = bf16(relu(mean + z)) in place over Z1b ----
    gather1_k<<<N / 8, 256, 0, stream>>>(row_ptr, csr, Y1, Z1b, inv, N);

    // ---- Layer 2 (MFMA, single-phase): Y2 + Z2b (both bf16) ----
    gemm2_k<<<(N + 127) / 128, 256, 0, stream>>>(Z1b, W2f, bl2, Y2, Z2b, N);

    // ---- out = log_softmax(mean2 + z2) ----
    gather2_logsm_k<<<(N + 15) / 16, 256, 0, stream>>>(row_ptr, csr, Y2, Z2b, inv, out, N);
}

// Round 8
// 240.832 us; speedup vs baseline: 16.9325x; 1.0266x over previous
//
#include <hip/hip_runtime.h>
#include <hip/hip_bf16.h>

#define N_NODES 100000
#define IN_C 256
#define HID 128
#define OUT_C 40

#define NPB 9
#define NPP (1 << NPB)                          // 512 nodes per partition
#define NPART ((N_NODES + NPP - 1) >> NPB)      // 196

typedef short bf16x8 __attribute__((ext_vector_type(8)));
typedef float f32x4 __attribute__((ext_vector_type(4)));

static __device__ __forceinline__ float bf2f(unsigned short u) {
    return __uint_as_float(((unsigned)u) << 16);
}
static __device__ __forceinline__ unsigned short f2bf(float f) {
    unsigned u = __float_as_uint(f);
    u += 0x7fffu + ((u >> 16) & 1u);
    return (unsigned short)(u >> 16);
}

// ---------------- A0: partition histogram ----------------
__global__ __launch_bounds__(256) void phist_k(const int* __restrict__ ei, int E, int* __restrict__ pcnt) {
    __shared__ int lh[NPART];
    int tid = threadIdx.x;
    if (tid < NPART) lh[tid] = 0;
    __syncthreads();
    int base = blockIdx.x * 4096;
    int n = min(4096, E - base);
    for (int i = tid; i < n; i += 256)
        atomicAdd(&lh[((unsigned)ei[E + base + i]) >> NPB], 1);
    __syncthreads();
    if (tid < NPART) {
        int c = lh[tid];
        if (c) atomicAdd(&pcnt[tid], c);
    }
}

// ---------------- A1: scan partition counts ----------------
__global__ __launch_bounds__(256) void pscan_k(const int* __restrict__ pcnt, int* __restrict__ pbase,
                                               int* __restrict__ pcur) {
    __shared__ int wsum[4];
    int t = threadIdx.x, lane = t & 63, w = t >> 6;
    int v = (t < NPART) ? pcnt[t] : 0;
    int s = v;
    #pragma unroll
    for (int off = 1; off < 64; off <<= 1) { int x = __shfl_up(s, off); if (lane >= off) s += x; }
    if (lane == 63) wsum[w] = s;
    __syncthreads();
    int woff = 0;
    for (int i = 0; i < w; ++i) woff += wsum[i];
    int excl = woff + s - v;
    if (t < NPART) { pbase[t] = excl; pcur[t] = excl; }
    if (t == 255) pbase[NPART] = woff + s;   // total = E
}

// ---------------- A2: scatter edges into partition-grouped packed pairs ----------------
__global__ __launch_bounds__(256) void pscatter_k(const int* __restrict__ ei, int E,
                                                  int* __restrict__ pcur, unsigned* __restrict__ pairs) {
    __shared__ int lh[NPART];
    __shared__ int lb[NPART];
    int tid = threadIdx.x;
    if (tid < NPART) lh[tid] = 0;
    __syncthreads();
    int base = blockIdx.x * 4096;
    int n = min(4096, E - base);
    for (int i = tid; i < n; i += 256)
        atomicAdd(&lh[((unsigned)ei[E + base + i]) >> NPB], 1);
    __syncthreads();
    if (tid < NPART) {
        int c = lh[tid];
        lb[tid] = c ? atomicAdd(&pcur[tid], c) : 0;
        lh[tid] = 0;
    }
    __syncthreads();
    for (int i = tid; i < n; i += 256) {
        unsigned src = (unsigned)ei[base + i];
        unsigned dst = (unsigned)ei[E + base + i];
        int p = dst >> NPB;
        int r = atomicAdd(&lh[p], 1);
        pairs[lb[p] + r] = (src << NPB) | (dst & (NPP - 1));
    }
}

// ---------------- B: per-partition CSR build (LDS count+scan+fill) ----------------
__global__ __launch_bounds__(256) void pbuild_k(const unsigned* __restrict__ pairs, const int* __restrict__ pbase,
                                                int* __restrict__ row_ptr, float* __restrict__ inv,
                                                int* __restrict__ csr, int N) {
    __shared__ int cnt[NPP];
    __shared__ int cur[NPP];
    __shared__ int wsum[4];
    int p = blockIdx.x;
    int ebeg = pbase[p], eend = pbase[p + 1];
    int node0 = p << NPB;
    int tid = threadIdx.x;
    cnt[2 * tid] = 0; cnt[2 * tid + 1] = 0;
    __syncthreads();
    for (int e = ebeg + tid; e < eend; e += 256)
        atomicAdd(&cnt[pairs[e] & (NPP - 1)], 1);
    __syncthreads();
    int c0 = cnt[2 * tid], c1 = cnt[2 * tid + 1];
    int s = c0 + c1;
    int lane = tid & 63, w = tid >> 6;
    int ps = s;
    #pragma unroll
    for (int off = 1; off < 64; off <<= 1) { int x = __shfl_up(ps, off); if (lane >= off) ps += x; }
    if (lane == 63) wsum[w] = ps;
    __syncthreads();
    int woff = 0;
    for (int i = 0; i < w; ++i) woff += wsum[i];
    int excl = woff + ps - s;
    int node = node0 + 2 * tid;
    if (node < N)     { row_ptr[node]     = ebeg + excl;      inv[node]     = 1.f / fmaxf((float)c0, 1.f); }
    if (node + 1 < N) { row_ptr[node + 1] = ebeg + excl + c0; inv[node + 1] = 1.f / fmaxf((float)c1, 1.f); }
    cur[2 * tid] = excl; cur[2 * tid + 1] = excl + c0;
    if (p == NPART - 1 && tid == 255) row_ptr[N] = eend;
    __syncthreads();
    for (int e = ebeg + tid; e < eend; e += 256) {
        unsigned pr = pairs[e];
        int r = atomicAdd(&cur[pr & (NPP - 1)], 1);
        csr[ebeg + r] = (int)(pr >> NPB);
    }
}

// ---------------- fused weight convert to fragment-major bf16 ----------------
__global__ __launch_bounds__(256) void cvtw_k(
    const float* __restrict__ Wl1, const float* __restrict__ Wr1,
    const float* __restrict__ Wl2, const float* __restrict__ Wr2,
    unsigned short* __restrict__ W1f, unsigned short* __restrict__ W2f)
{
    int gid = blockIdx.x * 256 + threadIdx.x;
    if (gid < 8192) {
        int g = gid;
        int ln = g & 63, blk = g >> 6;
        int c16 = blk >> 3, ks = blk & 7;
        int col = c16 * 16 + (ln & 15);
        int k0 = ks * 32 + (ln >> 4) * 8;
        const float* src = (col < 128) ? &Wl1[(size_t)col * 256 + k0]
                                       : &Wr1[(size_t)(col - 128) * 256 + k0];
        float4 v0 = *(const float4*)src;
        float4 v1 = *(const float4*)(src + 4);
        bf16x8 a;
        a[0] = (short)f2bf(v0.x); a[1] = (short)f2bf(v0.y);
        a[2] = (short)f2bf(v0.z); a[3] = (short)f2bf(v0.w);
        a[4] = (short)f2bf(v1.x); a[5] = (short)f2bf(v1.y);
        a[6] = (short)f2bf(v1.z); a[7] = (short)f2bf(v1.w);
        *(bf16x8*)&W1f[(size_t)g * 8] = a;
    } else if (gid < 9472) {
        int g = gid - 8192;
        int ln = g & 63, blk = g >> 6;
        int c16 = blk >> 2, ks = blk & 3;
        int col = c16 * 16 + (ln & 15);
        int k0 = ks * 32 + (ln >> 4) * 8;
        const float* src = (col < 40) ? &Wl2[(size_t)col * 128 + k0]
                                      : &Wr2[(size_t)(col - 40) * 128 + k0];
        float4 v0 = *(const float4*)src;
        float4 v1 = *(const float4*)(src + 4);
        bf16x8 a;
        a[0] = (short)f2bf(v0.x); a[1] = (short)f2bf(v0.y);
        a[2] = (short)f2bf(v0.z); a[3] = (short)f2bf(v0.w);
        a[4] = (short)f2bf(v1.x); a[5] = (short)f2bf(v1.y);
        a[6] = (short)f2bf(v1.z); a[7] = (short)f2bf(v1.w);
        *(bf16x8*)&W2f[(size_t)g * 8] = a;
    }
}

// ---------------- MFMA GEMM layer1, single-phase K=256, BM=64 (4 blocks/CU) ----------------
// X [M,256] f32; W1f fragment-major; Y1 = bf16(X@Wl^T), Z1b = bf16(X@Wr^T + b)
// 512 threads = 8 waves (2 row-halves of 32 x 4 col-quarters of 64)
__global__ __launch_bounds__(512) void gemm1_k(
    const float* __restrict__ X,
    const unsigned short* __restrict__ Wf,
    const float* __restrict__ bias,
    unsigned short* __restrict__ Y,
    unsigned short* __restrict__ Zb,
    int M)
{
    constexpr int KP = 264;                      // 256 + 8 pad
    __shared__ unsigned short As[64][KP];        // 33.8KB; reused as output tile [64][256]
    const int tx = threadIdx.x;
    const int rowTile = blockIdx.x * 64;
    const int wv = tx >> 6, ln = tx & 63;
    const int wr = wv >> 2;          // 0..1: 32-row half
    const int wc = wv & 3;           // 0..3: 64-col quarter
    const int lc = ln & 15, lk = (ln >> 4) * 8;

    // stage A: 64 rows x 256 k, 2048 granules of 8, 4 per thread
    float4 va[4], vb[4];
    #pragma unroll
    for (int i = 0; i < 4; ++i) {
        int g = i * 512 + tx;
        int r = g >> 5, kk = (g & 31) * 8;
        int gr = rowTile + r;
        if (gr < M) {
            const float* p = &X[(size_t)gr * 256 + kk];
            va[i] = *(const float4*)p;
            vb[i] = *(const float4*)(p + 4);
        } else {
            va[i] = make_float4(0.f, 0.f, 0.f, 0.f);
            vb[i] = make_float4(0.f, 0.f, 0.f, 0.f);
        }
    }
    #pragma unroll
    for (int i = 0; i < 4; ++i) {
        int g = i * 512 + tx;
        int r = g >> 5, kk = (g & 31) * 8;
        bf16x8 a;
        a[0] = (short)f2bf(va[i].x); a[1] = (short)f2bf(va[i].y);
        a[2] = (short)f2bf(va[i].z); a[3] = (short)f2bf(va[i].w);
        a[4] = (short)f2bf(vb[i].x); a[5] = (short)f2bf(vb[i].y);
        a[6] = (short)f2bf(vb[i].z); a[7] = (short)f2bf(vb[i].w);
        *(bf16x8*)&As[r][kk] = a;
    }
    __syncthreads();

    f32x4 acc[2][4] = {};
    #pragma unroll
    for (int ks = 0; ks < 8; ++ks) {
        int koff = ks * 32 + lk;
        bf16x8 bfr[4], af[2];
        #pragma unroll
        for (int n = 0; n < 4; ++n)
            bfr[n] = *(const bf16x8*)&Wf[(size_t)(((wc * 4 + n) * 8 + ks) * 512 + ln * 8)];
        #pragma unroll
        for (int m = 0; m < 2; ++m)
            af[m] = *(const bf16x8*)&As[wr * 32 + m * 16 + lc][koff];
        #pragma unroll
        for (int m = 0; m < 2; ++m)
            #pragma unroll
            for (int n = 0; n < 4; ++n)
                acc[m][n] = __builtin_amdgcn_mfma_f32_16x16x32_bf16(af[m], bfr[n], acc[m][n], 0, 0, 0);
    }

    // epilogue: acc -> LDS row-major bf16, then packed 16B coalesced stores
    __syncthreads();
    const int lr4 = (ln >> 4) * 4;
    #pragma unroll
    for (int m = 0; m < 2; ++m) {
        int r0 = wr * 32 + m * 16 + lr4;
        #pragma unroll
        for (int n = 0; n < 4; ++n) {
            int col = wc * 64 + n * 16 + lc;
            float b = (col >= 128) ? bias[col - 128] : 0.f;
            #pragma unroll
            for (int j = 0; j < 4; ++j)
                As[r0 + j][col] = f2bf(acc[m][n][j] + b);
        }
    }
    __syncthreads();
    #pragma unroll
    for (int i = 0; i < 4; ++i) {
        int g = i * 512 + tx;
        int r = g >> 5, c8 = (g & 31) * 8;
        int gr = rowTile + r;
        if (gr >= M) continue;
        bf16x8 v = *(const bf16x8*)&As[r][c8];
        if (c8 < 128) *(bf16x8*)&Y[(size_t)gr * 128 + c8] = v;
        else          *(bf16x8*)&Zb[(size_t)gr * 128 + (c8 - 128)] = v;
    }
}

// ---------------- MFMA GEMM layer2, single-phase K=128, LDS-transposed epilogue ----------------
__global__ __launch_bounds__(256) void gemm2_k(
    const unsigned short* __restrict__ Hb,
    const unsigned short* __restrict__ Wf,
    const float* __restrict__ bias,
    unsigned short* __restrict__ Y2,
    unsigned short* __restrict__ Z2b,
    int M)
{
    constexpr int KP = 136;                      // 128 + 8 pad
    __shared__ unsigned short As[128][KP];       // 34.8KB; reused as output tile [128][96]
    const int tx = threadIdx.x;
    const int rowTile = blockIdx.x * 128;
    const int wv = tx >> 6, ln = tx & 63;
    const int lc = ln & 15, lk = (ln >> 4) * 8;

    #pragma unroll
    for (int i = 0; i < 8; ++i) {
        int g = i * 256 + tx;
        int r = g >> 4, kk = (g & 15) * 8;
        int gr = rowTile + r;
        bf16x8 a = {};
        if (gr < M) a = *(const bf16x8*)&Hb[(size_t)gr * 128 + kk];
        *(bf16x8*)&As[r][kk] = a;
    }
    __syncthreads();

    f32x4 acc[2][5] = {};
    #pragma unroll
    for (int ks = 0; ks < 4; ++ks) {
        int koff = ks * 32 + lk;
        bf16x8 bfr[5], af[2];
        #pragma unroll
        for (int n = 0; n < 5; ++n)
            bfr[n] = *(const bf16x8*)&Wf[(size_t)((n * 4 + ks) * 512 + ln * 8)];
        #pragma unroll
        for (int m = 0; m < 2; ++m)
            af[m] = *(const bf16x8*)&As[wv * 32 + m * 16 + lc][koff];
        #pragma unroll
        for (int m = 0; m < 2; ++m)
            #pragma unroll
            for (int n = 0; n < 5; ++n)
                acc[m][n] = __builtin_amdgcn_mfma_f32_16x16x32_bf16(af[m], bfr[n], acc[m][n], 0, 0, 0);
    }

    __syncthreads();
    unsigned short (*OutL)[96] = (unsigned short (*)[96])&As[0][0];  // [128][96] bf16
    const int lr4 = (ln >> 4) * 4;
    #pragma unroll
    for (int m = 0; m < 2; ++m) {
        int r0 = wv * 32 + m * 16 + lr4;
        #pragma unroll
        for (int n = 0; n < 5; ++n) {
            int col = n * 16 + lc;
            float b = (col >= 40) ? bias[col - 40] : 0.f;
            #pragma unroll
            for (int j = 0; j < 4; ++j)
                OutL[r0 + j][col] = f2bf(acc[m][n][j] + b);
        }
    }
    __syncthreads();
    #pragma unroll
    for (int i = 0; i < 5; ++i) {
        int g = i * 256 + tx;            // 1280 granules = 128 rows x 10
        int r = g / 10, cg = g % 10;
        int c8 = cg * 8;
        int gr = rowTile + r;
        if (gr >= M) continue;
        bf16x8 v = *(const bf16x8*)&OutL[r][c8];
        if (c8 < 40) *(bf16x8*)&Y2[(size_t)gr * 40 + c8] = v;
        else         *(bf16x8*)&Z2b[(size_t)gr * 40 + (c8 - 40)] = v;
    }
}

// ---------------- gather layer 1: h = bf16(relu(mean(Y[src]) + Z)), in place over Zb ----------------
__global__ __launch_bounds__(256) void gather1_k(const int* __restrict__ row_ptr, const int* __restrict__ csr,
                                                 const unsigned short* __restrict__ Y,
                                                 unsigned short* __restrict__ Zb,
                                                 const float* __restrict__ inv, int n) {
    int node = blockIdx.x * 8 + (threadIdx.x >> 5);
    if (node >= n) return;
    int t = threadIdx.x & 31;
    int beg = row_ptr[node], end = row_ptr[node + 1];
    float a0 = 0.f, a1 = 0.f, a2 = 0.f, a3 = 0.f;
    int e = beg;
    for (; e + 4 <= end; e += 4) {
        int s0 = csr[e], s1 = csr[e + 1], s2 = csr[e + 2], s3 = csr[e + 3];
        ushort4 v0 = *(const ushort4*)&Y[(size_t)s0 * HID + t * 4];
        ushort4 v1 = *(const ushort4*)&Y[(size_t)s1 * HID + t * 4];
        ushort4 v2 = *(const ushort4*)&Y[(size_t)s2 * HID + t * 4];
        ushort4 v3 = *(const ushort4*)&Y[(size_t)s3 * HID + t * 4];
        a0 += bf2f(v0.x) + bf2f(v1.x) + bf2f(v2.x) + bf2f(v3.x);
        a1 += bf2f(v0.y) + bf2f(v1.y) + bf2f(v2.y) + bf2f(v3.y);
        a2 += bf2f(v0.z) + bf2f(v1.z) + bf2f(v2.z) + bf2f(v3.z);
        a3 += bf2f(v0.w) + bf2f(v1.w) + bf2f(v2.w) + bf2f(v3.w);
    }
    for (; e < end; ++e) {
        int s0 = csr[e];
        ushort4 v0 = *(const ushort4*)&Y[(size_t)s0 * HID + t * 4];
        a0 += bf2f(v0.x); a1 += bf2f(v0.y); a2 += bf2f(v0.z); a3 += bf2f(v0.w);
    }
    float iv = inv[node];
    ushort4 z = *(const ushort4*)&Zb[(size_t)node * HID + t * 4];
    ushort4 h;
    h.x = f2bf(fmaxf(a0 * iv + bf2f(z.x), 0.f));
    h.y = f2bf(fmaxf(a1 * iv + bf2f(z.y), 0.f));
    h.z = f2bf(fmaxf(a2 * iv + bf2f(z.z), 0.f));
    h.w = f2bf(fmaxf(a3 * iv + bf2f(z.w), 0.f));
    *(ushort4*)&Zb[(size_t)node * HID + t * 4] = h;
}

// ---------------- gather layer 2 + log_softmax ----------------
__global__ __launch_bounds__(256) void gather2_logsm_k(const int* __restrict__ row_ptr, const int* __restrict__ csr,
                                                       const unsigned short* __restrict__ Y,
                                                       const unsigned short* __restrict__ Zb,
                                                       const float* __restrict__ inv,
                                                       float* __restrict__ out, int n) {
    int node = blockIdx.x * 16 + (threadIdx.x >> 4);
    if (node >= n) return;
    int t = threadIdx.x & 15;
    float4 v = make_float4(-INFINITY, -INFINITY, -INFINITY, -INFINITY);
    if (t < 10) {
        int beg = row_ptr[node], end = row_ptr[node + 1];
        float4 acc = make_float4(0.f, 0.f, 0.f, 0.f);
        for (int e = beg; e < end; ++e) {
            int s = csr[e];
            ushort4 y = *(const ushort4*)&Y[(size_t)s * OUT_C + t * 4];
            acc.x += bf2f(y.x); acc.y += bf2f(y.y); acc.z += bf2f(y.z); acc.w += bf2f(y.w);
        }
        float iv = inv[node];
        ushort4 z = *(const ushort4*)&Zb[(size_t)node * OUT_C + t * 4];
        v.x = acc.x * iv + bf2f(z.x); v.y = acc.y * iv + bf2f(z.y);
        v.z = acc.z * iv + bf2f(z.z); v.w = acc.w * iv + bf2f(z.w);
    }
    float m = fmaxf(fmaxf(v.x, v.y), fmaxf(v.z, v.w));
    #pragma unroll
    for (int off = 8; off; off >>= 1) m = fmaxf(m, __shfl_xor(m, off, 16));
    float s4 = 0.f;
    if (t < 10) s4 = expf(v.x - m) + expf(v.y - m) + expf(v.z - m) + expf(v.w - m);
    #pragma unroll
    for (int off = 8; off; off >>= 1) s4 += __shfl_xor(s4, off, 16);
    float ls = m + logf(s4);
    if (t < 10) {
        float4 o;
        o.x = v.x - ls; o.y = v.y - ls; o.z = v.z - ls; o.w = v.w - ls;
        *(float4*)&out[(size_t)node * OUT_C + t * 4] = o;
    }
}

extern "C" void kernel_launch(void* const* d_in, const int* in_sizes, int n_in,
                              void* d_out, int out_size, void* d_ws, size_t ws_size,
                              hipStream_t stream) {
    const float* x   = (const float*)d_in[0];
    const int*   ei  = (const int*)d_in[1];
    const float* Wl1 = (const float*)d_in[2];
    const float* bl1 = (const float*)d_in[3];
    const float* Wr1 = (const float*)d_in[4];
    const float* Wl2 = (const float*)d_in[5];
    const float* bl2 = (const float*)d_in[6];
    const float* Wr2 = (const float*)d_in[7];
    float* out = (float*)d_out;
    const int N = N_NODES;
    const int E = in_sizes[1] / 2;

    char* ws = (char*)d_ws;
    int*   pcnt    = (int*)(ws + 0x0000);                   // [NPART]
    int*   pbase   = (int*)(ws + 0x1000);                   // [NPART+1]
    int*   pcur    = (int*)(ws + 0x2000);                   // [NPART]
    int*   row_ptr = (int*)(ws + 0x10000);                  // [N+1]
    float* inv     = (float*)(ws + 0x80000);                // [N]
    int*   csr     = (int*)(ws + 0x100000);                 // [E] 6.4MB (1MB..7.4MB)
    unsigned* pairs = (unsigned*)(ws + 0x800000);           // [E] 6.4MB packed, dead after pbuild
    unsigned short* Z2b = (unsigned short*)(ws + 0x800000); // [N,40] bf16 8MB, aliases pairs
    unsigned short* W1f = (unsigned short*)(ws + 0x1900000);// 128KB fragment-major
    unsigned short* W2f = (unsigned short*)(ws + 0x1930000);// 20KB fragment-major
    unsigned short* Y1  = (unsigned short*)(ws + 0x1A00000);// [N,128] bf16 25.6MB
    unsigned short* Z1b = (unsigned short*)(ws + 0x3500000);// [N,128] bf16 -> h in place
    unsigned short* Y2  = (unsigned short*)(ws + 0x5200000);// [N,40] bf16 8MB

    // ---- CSR build: partitioned counting sort (packed 32-bit pairs) ----
    hipMemsetAsync(pcnt, 0, NPART * 4, stream);
    int nblk = (E + 4095) / 4096;
    phist_k<<<nblk, 256, 0, stream>>>(ei, E, pcnt);
    pscan_k<<<1, 256, 0, stream>>>(pcnt, pbase, pcur);
    pscatter_k<<<nblk, 256, 0, stream>>>(ei, E, pcur, pairs);
    pbuild_k<<<NPART, 256, 0, stream>>>(pairs, pbase, row_ptr, inv, csr, N);

    // ---- fused weight conversion to fragment-major ----
    cvtw_k<<<37, 256, 0, stream>>>(Wl1, Wr1, Wl2, Wr2, W1f, W2f);

    // ---- Layer 1 (MFMA, single-phase, BM=64): Y1 + Z1b ----
    gemm1_k<<<(N + 63) / 64, 512, 0, stream>>>(x, W1f, bl1, Y1, Z1b, N);

    // ---- h = bf16(relu(mean + z)) in place over Z1b ----
    gather1_k<<<N / 8, 256, 0, stream>>>(row_ptr, csr, Y1, Z1b, inv, N);

    // ---- Layer 2 (MFMA, single-phase): Y2 + Z2b (both bf16) ----
    gemm2_k<<<(N + 127) / 128, 256, 0, stream>>>(Z1b, W2f, bl2, Y2, Z2b, N);

    // ---- out = log_softmax(mean2 + z2) ----
    gather2_logsm_k<<<(N + 15) / 16, 256, 0, stream>>>(row_ptr, csr, Y2, Z2b, inv, out, N);
}